// Round 14
// baseline (122.909 us; speedup 1.0000x reference)
//
#include <hip/hip_runtime.h>
#include <stdint.h>

#define TAGS 10
#define START_TAG 8
#define STOP_TAG 9
#define NEGV (-10000.0f)

// DPP within 16-lane rows: ROW_ROR:r = 0x120+r, QUAD_PERM[1,0,3,2] = 0xB1.
#define DPP_I(x, ctrl) __builtin_amdgcn_update_dpp(0, (x), (ctrl), 0xF, 0xF, true)

__device__ __forceinline__ float maxf3(float a, float b, float c) {
    return fmaxf(fmaxf(a, b), c);   // folds to v_max3_f32
}

// Inline-asm feat loads: structurally pinned (regalloc cannot sink them).
#define GLOADI(dst, base, OFF) \
    asm volatile("global_load_dword %0, %1, off offset:" #OFF \
                 : "=v"(dst) : "v"(base))
#define GLOAD8(BUF, BASE) { \
    const float* gb_ = (BASE); \
    GLOADI(BUF[0], gb_, 0);   GLOADI(BUF[1], gb_, 40); \
    GLOADI(BUF[2], gb_, 80);  GLOADI(BUF[3], gb_, 120); \
    GLOADI(BUF[4], gb_, 160); GLOADI(BUF[5], gb_, 200); \
    GLOADI(BUF[6], gb_, 240); GLOADI(BUF[7], gb_, 280); }
#define GLOAD8X(BUF, FB, TB) { \
    GLOADI(BUF[0], (FB) + (size_t)min(max((TB) + 0, 0), T - 1) * TAGS, 0); \
    GLOADI(BUF[1], (FB) + (size_t)min(max((TB) + 1, 0), T - 1) * TAGS, 0); \
    GLOADI(BUF[2], (FB) + (size_t)min(max((TB) + 2, 0), T - 1) * TAGS, 0); \
    GLOADI(BUF[3], (FB) + (size_t)min(max((TB) + 3, 0), T - 1) * TAGS, 0); \
    GLOADI(BUF[4], (FB) + (size_t)min(max((TB) + 4, 0), T - 1) * TAGS, 0); \
    GLOADI(BUF[5], (FB) + (size_t)min(max((TB) + 5, 0), T - 1) * TAGS, 0); \
    GLOADI(BUF[6], (FB) + (size_t)min(max((TB) + 6, 0), T - 1) * TAGS, 0); \
    GLOADI(BUF[7], (FB) + (size_t)min(max((TB) + 7, 0), T - 1) * TAGS, 0); }
// Exact steady-state wait (R13-proven): one dummy store in the prologue makes
// the newest-17 window always {cur 8 loads, prev store, prev 8 loads}.
#define WAITP { asm volatile("s_waitcnt vmcnt(17)" ::: "memory"); \
                __builtin_amdgcn_sched_barrier(0); }
#define PINFENCE __builtin_amdgcn_sched_barrier(0);

// ===========================================================================
// K1: 2-way meet-in-the-middle. Blocks [0,ABLK): FORWARD Viterbi t in [0,H),
// 4 seqs/wave (16-lane duplicated octets, R12-proven chunk-A). Blocks
// [ABLK,2*ABLK): BACKWARD Viterbi t in [T-2 .. H-1], same layout (R12-proven
// chunk-C): h_t[m] = max_q(feat_{t+1}[q] + h_{t+1}[q] + trans[q][m]), init
// h = trans[STOP][:] at t = len-1 (steps with t >= len-1 inactive). No basis
// chunk: the backward boundary condition is known at the end. Outputs:
// bpA/bpC nibble-block backpointers, fvAo = fv at H-1, hws = h at H-1.
// ===========================================================================
__global__ __launch_bounds__(64, 1) void crf_fb_fwd(
    const float* __restrict__ feats,
    const int*   __restrict__ lengths,
    const float* __restrict__ trans,
    uint8_t*     __restrict__ bpA,
    uint8_t*     __restrict__ bpC,
    float*       __restrict__ fvAo,
    float*       __restrict__ hws,
    int B, int T, int H, int ABLK, int NCpad)
{
    const int lane = threadIdx.x & 63;
    const int grp  = lane >> 4;
    const int n    = lane & 15;
    const int m    = n & 7;
    const bool odd = (n & 1);

    // srcv[r] = source lane delivered by ROW_ROR:r (convention-proof)
    int srcv[8];
    srcv[0] = n;
    srcv[1] = DPP_I(n, 0x121);  srcv[2] = DPP_I(n, 0x122);
    srcv[3] = DPP_I(n, 0x123);  srcv[4] = DPP_I(n, 0x124);
    srcv[5] = DPP_I(n, 0x125);  srcv[6] = DPP_I(n, 0x126);
    srcv[7] = DPP_I(n, 0x127);

    int rsrc[8];
#pragma unroll
    for (int r = 0; r < 8; ++r) rsrc[r] = (srcv[r] & 7) ^ 7;

    if ((int)blockIdx.x < ABLK) {
        // ---------------- forward: t in [0, H) ----------------
        const int b4   = blockIdx.x * 4;
        const int b    = min(b4 + grp, B - 1);
        const int len  = lengths[b];
        const int lenA = min(len, H);
        const int l0 = lengths[min(b4 + 0, B - 1)];
        const int l1 = lengths[min(b4 + 1, B - 1)];
        const int l2 = lengths[min(b4 + 2, B - 1)];
        const int l3 = lengths[min(b4 + 3, B - 1)];
        const int HA = min(max(max(l0, l1), max(l2, l3)), H);
        const int blocksA = (H + 6) >> 3;

        float trowR[8];
#pragma unroll
        for (int r = 0; r < 8; ++r)
            trowR[r] = trans[m * TAGS + (srcv[r] & 7)];

        const float* fb = feats + (size_t)b * T * TAGS + m;
        uint8_t* bpa_l = bpA + (size_t)b * blocksA * 32 + ((n >> 1) & 3) * 8;
        const bool stl = (n < 8) && !odd;

        float fv = trans[m * TAGS + START_TAG] + fb[0];   // t=0 closed form

#define KLEAF_A(r, ctrl) { \
        int rot_ = DPP_I(__float_as_int(fv), (ctrl)); \
        float lv_ = __int_as_float(rot_) + trowR[r]; \
        k##r = __int_as_float((__float_as_int(lv_) & ~7) | rsrc[r]); }

#define STEP_A(TI, FEAT, ACCST) { \
        const int t_ = (TI); \
        float k0, k1, k2, k3, k4, k5, k6, k7; \
        { float lv_ = fv + trowR[0]; \
          k0 = __int_as_float((__float_as_int(lv_) & ~7) | rsrc[0]); } \
        KLEAF_A(1, 0x121) KLEAF_A(2, 0x122) KLEAF_A(3, 0x123) \
        KLEAF_A(4, 0x124) KLEAF_A(5, 0x125) KLEAF_A(6, 0x126) \
        KLEAF_A(7, 0x127) \
        const float p1_ = maxf3(k0, k1, k2); \
        const float p2_ = maxf3(k3, k4, k5); \
        const float p3_ = maxf3(k6, k7, p1_); \
        const float mm_ = fmaxf(p2_, p3_); \
        const int idx_  = (__float_as_int(mm_) & 7) ^ 7; \
        const int pidx_ = DPP_I(idx_, 0xB1); \
        const uint32_t byte_ = (uint32_t)(odd ? (pidx_ | (idx_ << 4)) \
                                              : (idx_ | (pidx_ << 4))); \
        ACCST; \
        const float fvn_ = mm_ + (FEAT); \
        fv = (t_ < lenA) ? fvn_ : fv; }

#define PH_A(USE, LD, T0) { \
        GLOAD8(LD, fb + (size_t)min((T0) + 16, T - 8) * TAGS); \
        WAITP \
        uint32_t accl, acch; \
        STEP_A((T0) + 0, USE[0], accl = byte_) \
        STEP_A((T0) + 1, USE[1], accl |= byte_ << 8) \
        STEP_A((T0) + 2, USE[2], accl |= byte_ << 16) \
        STEP_A((T0) + 3, USE[3], accl |= byte_ << 24) \
        STEP_A((T0) + 4, USE[4], acch = byte_) \
        STEP_A((T0) + 5, USE[5], acch |= byte_ << 8) \
        STEP_A((T0) + 6, USE[6], acch |= byte_ << 16) \
        STEP_A((T0) + 7, USE[7], acch |= byte_ << 24) \
        if ((T0) < H) { \
            if (stl) *(uint2*)(bpa_l + (size_t)(((T0) - 1) >> 3) * 32) \
                         = make_uint2(accl, acch); } }

        PINFENCE
        float xb[8], yb[8], zb[8];
        GLOAD8(xb, fb + (size_t)1 * TAGS);
        GLOAD8(yb, fb + (size_t)min(9, T - 8) * TAGS);
        if (n < 8) *(volatile float*)(fvAo + (size_t)b * 8 + m) = 0.0f; // vmcnt dummy

        for (int t0 = 1; t0 < HA; t0 += 24) {
            PH_A(xb, zb, t0)
            PH_A(yb, xb, t0 + 8)
            PH_A(zb, yb, t0 + 16)
        }
#undef KLEAF_A
#undef STEP_A
#undef PH_A

        if (n < 8)
            fvAo[(size_t)b * 8 + m] = fv;
    } else {
        // ---------------- backward: t in [T-2 .. H-1] ----------------
        const int c4   = (blockIdx.x - ABLK) * 4;
        const int b    = min(c4 + grp, B - 1);
        const int len  = lengths[b];
        const int lenm1 = len - 1;           // step t active iff t < len-1
        const int l0 = lengths[min(c4 + 0, B - 1)];
        const int l1 = lengths[min(c4 + 1, B - 1)];
        const int l2 = lengths[min(c4 + 2, B - 1)];
        const int l3 = lengths[min(c4 + 3, B - 1)];
        const int maxlen = max(max(l0, l1), max(l2, l3));

        // blocks above the 4-seq max length are all-inactive: skip them.
        // k covers t in [H-1+8k, H-1+8k+7]; need top k with H-1+8k <= maxlen-2.
        const int ktop = (maxlen > H) ? min(NCpad - 1, (maxlen - H - 1) >> 3) : -1;
        const int k0 = ((ktop + 3) / 3) * 3 - 1;   // round up to ==2 (mod 3)

        float trowC[8];
#pragma unroll
        for (int r = 0; r < 8; ++r)
            trowC[r] = trans[(srcv[r] & 7) * TAGS + m];

        float h = trans[STOP_TAG * TAGS + m];   // init at t = len-1
        const float* fb = feats + (size_t)b * T * TAGS + m;
        uint8_t* bpc_l = bpC + (size_t)b * NCpad * 32 + ((n >> 1) & 3) * 8;
        const bool stl = (n < 8) && !odd;

#define KLEAF_C(r, ctrl) { \
        int rot_ = DPP_I(__float_as_int(e_), (ctrl)); \
        float lv_ = __int_as_float(rot_) + trowC[r]; \
        k##r = __int_as_float((__float_as_int(lv_) & ~7) | rsrc[r]); }

#define STEP_C(K, J, FEAT, ACCST) { \
        const int t_ = H - 1 + 8 * (K) + (J); \
        const float e_ = h + (FEAT); \
        float k0, k1, k2, k3, k4, k5, k6, k7; \
        { float lv_ = e_ + trowC[0]; \
          k0 = __int_as_float((__float_as_int(lv_) & ~7) | rsrc[0]); } \
        KLEAF_C(1, 0x121) KLEAF_C(2, 0x122) KLEAF_C(3, 0x123) \
        KLEAF_C(4, 0x124) KLEAF_C(5, 0x125) KLEAF_C(6, 0x126) \
        KLEAF_C(7, 0x127) \
        const float p1_ = maxf3(k0, k1, k2); \
        const float p2_ = maxf3(k3, k4, k5); \
        const float p3_ = maxf3(k6, k7, p1_); \
        const float mm_ = fmaxf(p2_, p3_); \
        const int idx_  = (__float_as_int(mm_) & 7) ^ 7; \
        const int pidx_ = DPP_I(idx_, 0xB1); \
        const uint32_t byte_ = (uint32_t)(odd ? (pidx_ | (idx_ << 4)) \
                                              : (idx_ | (pidx_ << 4))); \
        ACCST; \
        h = (t_ < lenm1) ? mm_ : h; }

#define PH_C(USE, LD, K) { \
        GLOAD8X(LD, fb, H + 8 * ((K) - 2)) \
        WAITP \
        uint32_t accl, acch; \
        STEP_C(K, 7, USE[7], acch = byte_ << 24) \
        STEP_C(K, 6, USE[6], acch |= byte_ << 16) \
        STEP_C(K, 5, USE[5], acch |= byte_ << 8) \
        STEP_C(K, 4, USE[4], acch |= byte_) \
        STEP_C(K, 3, USE[3], accl = byte_ << 24) \
        STEP_C(K, 2, USE[2], accl |= byte_ << 16) \
        STEP_C(K, 1, USE[1], accl |= byte_ << 8) \
        STEP_C(K, 0, USE[0], accl |= byte_) \
        if (stl) *(uint2*)(bpc_l + (size_t)(K) * 32) = make_uint2(accl, acch); }

        PINFENCE
        float xb[8], yb[8], zb[8];
        GLOAD8X(xb, fb, H + 8 * k0)
        GLOAD8X(yb, fb, H + 8 * (k0 - 1))
        if (n < 8) *(volatile float*)(hws + (size_t)b * 8 + m) = 0.0f; // vmcnt dummy

        for (int k = k0; k >= 0; k -= 3) {   // k0 == 2 (mod 3)
            PH_C(xb, zb, k)
            PH_C(yb, xb, k - 1)
            PH_C(zb, yb, k - 2)
        }
#undef KLEAF_C
#undef STEP_C
#undef PH_C

        if (n < 8)
            hws[(size_t)b * 8 + m] = h;      // h at t = H-1
    }
}

// ===========================================================================
// K2: seam compose + two backtrace roles per sequence.
// compose: score = max_n(fv_{H-1}[n] + h_{H-1}[n]); b* = first-index argmax.
// For len <= H, h == STOP row => exact reference terminal. role A: walk
// [0,H) down from b*. role C: write score + walk path[H..T) forward via
// backward backpointers: s_{t+1} = bb_t[s_t], starting s_{H-1} = b*.
// ===========================================================================
__global__ __launch_bounds__(64, 1) void crf_fb_bt(
    const int*     __restrict__ lengths,
    const uint8_t* __restrict__ bpA,
    const uint8_t* __restrict__ bpC,
    const float*   __restrict__ fvA,
    const float*   __restrict__ hws,
    float*         __restrict__ out_scores,
    float*         __restrict__ out_path,
    int B, int T, int H, int NCpad)
{
    const int rb = (B + 63) >> 6;
    const bool roleA = ((int)blockIdx.x < rb);
    const int s = (roleA ? (int)blockIdx.x : (int)blockIdx.x - rb) * 64 + threadIdx.x;
    if (s >= B) return;
    const int len = lengths[s];
    const int blocksA = (H + 6) >> 3;

    // compose
    float fa[8], hh[8];
    {
        const float4* f4 = (const float4*)(fvA + (size_t)s * 8);
        float4 a = f4[0], c = f4[1];
        fa[0]=a.x; fa[1]=a.y; fa[2]=a.z; fa[3]=a.w;
        fa[4]=c.x; fa[5]=c.y; fa[6]=c.z; fa[7]=c.w;
        const float4* h4 = (const float4*)(hws + (size_t)s * 8);
        float4 d = h4[0], e = h4[1];
        hh[0]=d.x; hh[1]=d.y; hh[2]=d.z; hh[3]=d.w;
        hh[4]=e.x; hh[5]=e.y; hh[6]=e.z; hh[7]=e.w;
    }
    float best = fa[0] + hh[0];
    int bstar = 0;
#pragma unroll
    for (int nn = 1; nn < 8; ++nn) {
        const float v = fa[nn] + hh[nn];
        if (v > best) { best = v; bstar = nn; }
    }

    float* orow = out_path + (size_t)s * T;

#define CHASE(J) { \
        const uint32_t sA_ = (tag & 2) ? d[2 + ((J) >> 2)] : d[((J) >> 2)]; \
        const uint32_t sB_ = (tag & 2) ? d[6 + ((J) >> 2)] : d[4 + ((J) >> 2)]; \
        const uint32_t sel_ = (tag & 4) ? sB_ : sA_; \
        tag = (int)((sel_ >> (8 * ((J) & 3) + 4 * (tag & 1))) & 7); }

    if (roleA) {
        const int lenA = min(len, H);
        int tag = bstar;
        const uint8_t* ab8 = bpA + (size_t)s * blocksA * 32;
        uint4 a0, c0, a1, c1;
        auto ldA = [&](int k, uint4& qa, uint4& qb) {
            if (k < 0) return;
            qa = *(const uint4*)(ab8 + (size_t)k * 32);
            qb = *(const uint4*)(ab8 + (size_t)k * 32 + 16);
        };
        auto cpA = [&](int k, const uint4& qa, const uint4& qb) {
            const uint32_t d[8] = {qa.x, qa.y, qa.z, qa.w, qb.x, qb.y, qb.z, qb.w};
#pragma unroll
            for (int u = 7; u >= 0; --u) {
                const int t = 8 * k + 1 + u;
                if (t < H) {
                    const bool act = t < lenA;
                    orow[t] = act ? (float)tag : 0.0f;
                    if (act) CHASE(u)
                }
            }
        };
        int k = blocksA - 1;
        ldA(k, a0, c0); ldA(k - 1, a1, c1);
        for (; k >= 0; k -= 2) {
            cpA(k, a0, c0); ldA(k - 2, a0, c0);
            if (k - 1 >= 0) cpA(k - 1, a1, c1);
            ldA(k - 3, a1, c1);
        }
        orow[0] = (float)tag;               // state at t=0
    } else {
        out_scores[s] = best;
        int tag = bstar;                    // state at t = H-1
        const int NCu = (T - H + 7) >> 3;
        const uint8_t* cb8 = bpC + (size_t)s * NCpad * 32;
        uint4 a0, c0, a1, c1;
        auto ldC = [&](int k, uint4& qa, uint4& qb) {
            if (k >= NCu) return;
            qa = *(const uint4*)(cb8 + (size_t)k * 32);
            qb = *(const uint4*)(cb8 + (size_t)k * 32 + 16);
        };
        auto cpC = [&](int k, const uint4& qa, const uint4& qb) {
            const uint32_t d[8] = {qa.x, qa.y, qa.z, qa.w, qb.x, qb.y, qb.z, qb.w};
            float buf[8];
#pragma unroll
            for (int j = 0; j < 8; ++j) {
                const int t = H - 1 + 8 * k + j;
                const bool act = t < len - 1;   // bb_t valid for t <= len-2
                if (act) { CHASE(j) buf[j] = (float)tag; }
                else buf[j] = 0.0f;
            }
            const int p0 = H + 8 * k;           // path index = t+1
            if (p0 + 7 < T) {
                *(float4*)(orow + p0)     = make_float4(buf[0], buf[1], buf[2], buf[3]);
                *(float4*)(orow + p0 + 4) = make_float4(buf[4], buf[5], buf[6], buf[7]);
            } else {
#pragma unroll
                for (int j = 0; j < 8; ++j)
                    if (p0 + j < T) orow[p0 + j] = buf[j];
            }
        };
        int k = 0;
        ldC(0, a0, c0); ldC(1, a1, c1);
        for (; k < NCu; k += 2) {
            cpC(k, a0, c0); ldC(k + 2, a0, c0);
            if (k + 1 < NCu) cpC(k + 1, a1, c1);
            ldC(k + 3, a1, c1);
        }
    }
#undef CHASE
}

// ===========================================================================
// Fallback (ws too small / odd shapes): R8 fused kernel verbatim.
// ===========================================================================
__global__ __launch_bounds__(64, 1) void crf_fused_small(
    const float* __restrict__ feats,
    const int*   __restrict__ lengths,
    const float* __restrict__ trans,
    float*       __restrict__ out_scores,
    float*       __restrict__ out_path,
    uint8_t*     __restrict__ bp4,
    int B, int T)
{
    const int lane = threadIdx.x & 63;
    const int grp  = lane >> 4;
    const int n    = lane & 15;
    const int m    = n & 7;
    const bool odd = (n & 1);
    const int b4   = blockIdx.x * 4;
    const int b    = min(b4 + grp, B - 1);

    const int len = lengths[b];
    const int l0 = lengths[min(b4 + 0, B - 1)];
    const int l1 = lengths[min(b4 + 1, B - 1)];
    const int l2 = lengths[min(b4 + 2, B - 1)];
    const int l3 = lengths[min(b4 + 3, B - 1)];
    const int maxlen = max(max(l0, l1), max(l2, l3));

    int srcv[8];
    srcv[0] = n;
    srcv[1] = DPP_I(n, 0x121);  srcv[2] = DPP_I(n, 0x122);
    srcv[3] = DPP_I(n, 0x123);  srcv[4] = DPP_I(n, 0x124);
    srcv[5] = DPP_I(n, 0x125);  srcv[6] = DPP_I(n, 0x126);
    srcv[7] = DPP_I(n, 0x127);

    float trowR[8];
    int   rsrc[8];
#pragma unroll
    for (int r = 0; r < 8; ++r) {
        const int sq = srcv[r] & 7;
        trowR[r] = trans[m * TAGS + sq];
        rsrc[r]  = sq ^ 7;
    }

    const float* fb = feats + (size_t)b * T * TAGS + m;
    uint8_t* bpb = bp4 + (size_t)b * T * 4 + (n >> 1);
    const bool store_lane = (n < 8) && !odd;

    float fv = trans[m * TAGS + START_TAG] + fb[0];

#define KLEAF_S(r, ctrl) { \
        int rot_ = DPP_I(__float_as_int(fv), (ctrl)); \
        float lv_ = __int_as_float(rot_) + trowR[r]; \
        k##r = __int_as_float((__float_as_int(lv_) & ~7) | rsrc[r]); }

#define STEP_S(TI, FEAT) { \
        const int t_ = (TI); \
        float k0, k1, k2, k3, k4, k5, k6, k7; \
        { float lv_ = fv + trowR[0]; \
          k0 = __int_as_float((__float_as_int(lv_) & ~7) | rsrc[0]); } \
        KLEAF_S(1, 0x121) KLEAF_S(2, 0x122) KLEAF_S(3, 0x123) \
        KLEAF_S(4, 0x124) KLEAF_S(5, 0x125) KLEAF_S(6, 0x126) \
        KLEAF_S(7, 0x127) \
        const float p1_ = maxf3(k0, k1, k2); \
        const float p2_ = maxf3(k3, k4, k5); \
        const float p3_ = maxf3(k6, k7, p1_); \
        const float mm_ = fmaxf(p2_, p3_); \
        const int   idx_  = (__float_as_int(mm_) & 7) ^ 7; \
        const int   pidx_ = DPP_I(idx_, 0xB1); \
        const int   lo_   = odd ? pidx_ : idx_; \
        const int   hi_   = odd ? idx_ : pidx_; \
        const float fvn_  = mm_ + (FEAT); \
        fv = (t_ < len) ? fvn_ : fv; \
        if (t_ < T) { \
            if (store_lane) \
                bpb[(size_t)t_ * 4] = (uint8_t)(lo_ | (hi_ << 4)); \
        } }

    float fc[8], fn[8];
#pragma unroll
    for (int i = 0; i < 8; ++i)
        fc[i] = fb[(size_t)min(1 + i, T - 1) * TAGS];

    for (int t0 = 1; t0 < maxlen; t0 += 8) {
#pragma unroll
        for (int i = 0; i < 8; ++i)
            fn[i] = fb[(size_t)min(t0 + 8 + i, T - 1) * TAGS];

        STEP_S(t0 + 0, fc[0]) STEP_S(t0 + 1, fc[1])
        STEP_S(t0 + 2, fc[2]) STEP_S(t0 + 3, fc[3])
        STEP_S(t0 + 4, fc[4]) STEP_S(t0 + 5, fc[5])
        STEP_S(t0 + 6, fc[6]) STEP_S(t0 + 7, fc[7])

#pragma unroll
        for (int i = 0; i < 8; ++i) fc[i] = fn[i];
    }
#undef KLEAF_S
#undef STEP_S

    const float term = fv + trans[STOP_TAG * TAGS + m];
    float kk = __int_as_float((__float_as_int(term) & ~7) | (m ^ 7));
    kk = fmaxf(kk, __int_as_float(DPP_I(__float_as_int(kk), 0x124)));
    kk = fmaxf(kk, __int_as_float(DPP_I(__float_as_int(kk), 0x122)));
    kk = fmaxf(kk, __int_as_float(DPP_I(__float_as_int(kk), 0x121)));
    int tag = (__float_as_int(kk) & 7) ^ 7;

    if (n == 0)
        out_scores[b] = kk;

    __builtin_amdgcn_s_waitcnt(0);
    __builtin_amdgcn_sched_barrier(0);

    if (n == 0) {
        const uint32_t* rw = (const uint32_t*)(bp4 + (size_t)b * T * 4);
        float* orow = out_path + (size_t)b * T;
        const int NB = (T + 15) / 16;
        uint32_t wA[16], wB[16];

        auto loadblk = [&](int bi, uint32_t* w) {
            if (bi < 0) return;
#pragma unroll
            for (int j = 0; j < 4; ++j) {
                const int tb = min(bi * 16 + 4 * j, T - 4);
                *(uint4*)&w[4 * j] = *(const uint4*)&rw[tb];
            }
        };
        auto compblk = [&](int bi, uint32_t* w) {
            float buf[16];
#pragma unroll
            for (int u = 15; u >= 0; --u) {
                const int t = bi * 16 + u;
                if (t < T) {
                    const bool act = t < len;
                    buf[u] = act ? (float)tag : 0.0f;
                    if (act) tag = (int)((w[u] >> (4 * tag)) & 15);
                }
            }
#pragma unroll
            for (int j = 0; j < 16; j += 4) {
                const int t = bi * 16 + j;
                if (t + 3 < T)
                    *(float4*)(orow + t) = make_float4(buf[j], buf[j+1], buf[j+2], buf[j+3]);
            }
        };

        int bi = NB - 1;
        loadblk(bi, wA);
        loadblk(bi - 1, wB);
        for (; bi >= 0; bi -= 2) {
            compblk(bi, wA);
            loadblk(bi - 2, wA);
            if (bi - 1 >= 0) compblk(bi - 1, wB);
            loadblk(bi - 3, wB);
        }
    }
}

extern "C" void kernel_launch(void* const* d_in, const int* in_sizes, int n_in,
                              void* d_out, int out_size, void* d_ws, size_t ws_size,
                              hipStream_t stream)
{
    const float* feats   = (const float*)d_in[0];
    const int*   lengths = (const int*)d_in[1];
    const float* trans   = (const float*)d_in[2];
    const int B = in_sizes[1];
    const int T = in_sizes[0] / (B * TAGS);

    float* out_scores = (float*)d_out;       // [B]
    float* out_path   = (float*)d_out + B;   // [B, T] tags as floats

    const int H = ((T / 2) + 15) & ~15;      // seam, multiple of 16
    const int blocksA = (H + 6) >> 3;
    const int NC  = (T - H + 7) >> 3;
    const int NCpad = ((NC + 2) / 3) * 3;

    const size_t szA = (size_t)B * blocksA * 32;
    const size_t szC = (size_t)B * NCpad * 32;
    const size_t need = szA + szC + (size_t)B * 64;

    if (H >= 16 && T > H + 1 && (T & 3) == 0 && (B & 3) == 0 && need <= ws_size) {
        uint8_t* bpA  = (uint8_t*)d_ws;
        uint8_t* bpC  = bpA + szA;
        float*   fvAo = (float*)(bpC + szC);
        float*   hws  = fvAo + (size_t)B * 8;
        const int ABLK = B / 4;

        crf_fb_fwd<<<2 * ABLK, 64, 0, stream>>>(
            feats, lengths, trans, bpA, bpC, fvAo, hws, B, T, H, ABLK, NCpad);

        const int rb = (B + 63) >> 6;
        crf_fb_bt<<<2 * rb, 64, 0, stream>>>(
            lengths, bpA, bpC, fvAo, hws, out_scores, out_path, B, T, H, NCpad);
    } else {
        uint8_t* bp4 = (uint8_t*)d_ws;       // [B][T] 4B words
        crf_fused_small<<<(B + 3) / 4, 64, 0, stream>>>(
            feats, lengths, trans, out_scores, out_path, bp4, B, T);
    }
}

// Round 15
// 74.138 us; speedup vs baseline: 1.6578x; 1.6578x over previous
//
#include <hip/hip_runtime.h>
#include <stdint.h>

#define TAGS 10
#define START_TAG 8
#define STOP_TAG 9
#define NEGV (-10000.0f)

// DPP within 16-lane rows: ROW_ROR:r = 0x120+r, QUAD_PERM[1,0,3,2] = 0xB1.
#define DPP_I(x, ctrl) __builtin_amdgcn_update_dpp(0, (x), (ctrl), 0xF, 0xF, true)

typedef int v4i __attribute__((ext_vector_type(4)));

__device__ __forceinline__ float maxf3(float a, float b, float c) {
    return fmaxf(fmaxf(a, b), c);   // folds to v_max3_f32
}

// Inline-asm loads: structurally pinned in VGPRs (regalloc cannot sink or
// spill them — R14's K2 lambda-uint4& buffers were demoted to LDS: VGPR=20,
// LDS=4096, 84k bank conflicts, 74us).
#define GLOADI(dst, base, OFF) \
    asm volatile("global_load_dword %0, %1, off offset:" #OFF \
                 : "=v"(dst) : "v"(base))
#define GLOADQ(dst, addr) \
    asm volatile("global_load_dwordx4 %0, %1, off" \
                 : "=v"(dst) : "v"((const void*)(addr)) : "memory")
#define GLOAD8(BUF, BASE) { \
    const float* gb_ = (BASE); \
    GLOADI(BUF[0], gb_, 0);   GLOADI(BUF[1], gb_, 40); \
    GLOADI(BUF[2], gb_, 80);  GLOADI(BUF[3], gb_, 120); \
    GLOADI(BUF[4], gb_, 160); GLOADI(BUF[5], gb_, 200); \
    GLOADI(BUF[6], gb_, 240); GLOADI(BUF[7], gb_, 280); }
#define GLOAD8X(BUF, FB, TB) { \
    GLOADI(BUF[0], (FB) + (size_t)min(max((TB) + 0, 0), T - 1) * TAGS, 0); \
    GLOADI(BUF[1], (FB) + (size_t)min(max((TB) + 1, 0), T - 1) * TAGS, 0); \
    GLOADI(BUF[2], (FB) + (size_t)min(max((TB) + 2, 0), T - 1) * TAGS, 0); \
    GLOADI(BUF[3], (FB) + (size_t)min(max((TB) + 3, 0), T - 1) * TAGS, 0); \
    GLOADI(BUF[4], (FB) + (size_t)min(max((TB) + 4, 0), T - 1) * TAGS, 0); \
    GLOADI(BUF[5], (FB) + (size_t)min(max((TB) + 5, 0), T - 1) * TAGS, 0); \
    GLOADI(BUF[6], (FB) + (size_t)min(max((TB) + 6, 0), T - 1) * TAGS, 0); \
    GLOADI(BUF[7], (FB) + (size_t)min(max((TB) + 7, 0), T - 1) * TAGS, 0); }
// K1 steady-state exact wait (R13-proven): one dummy store in the prologue
// makes the newest-17 window {cur 8 loads, prev store, prev 8 loads}.
#define WAITP { asm volatile("s_waitcnt vmcnt(17)" ::: "memory"); \
                __builtin_amdgcn_sched_barrier(0); }
#define PINFENCE __builtin_amdgcn_sched_barrier(0);

// ===========================================================================
// K1: 2-way meet-in-the-middle forward pass (R14 structure; chunk-A phases
// now start at t0=0 so bp block k holds steps t = 8k..8k+7 — aligned for
// K2's vectorized walk; step 0's bp byte is garbage and never chased).
// ===========================================================================
__global__ __launch_bounds__(64, 1) void crf_fb_fwd(
    const float* __restrict__ feats,
    const int*   __restrict__ lengths,
    const float* __restrict__ trans,
    uint8_t*     __restrict__ bpA,
    uint8_t*     __restrict__ bpC,
    float*       __restrict__ fvAo,
    float*       __restrict__ hws,
    int B, int T, int H, int ABLK, int NCpad)
{
    const int lane = threadIdx.x & 63;
    const int grp  = lane >> 4;
    const int n    = lane & 15;
    const int m    = n & 7;
    const bool odd = (n & 1);

    int srcv[8];
    srcv[0] = n;
    srcv[1] = DPP_I(n, 0x121);  srcv[2] = DPP_I(n, 0x122);
    srcv[3] = DPP_I(n, 0x123);  srcv[4] = DPP_I(n, 0x124);
    srcv[5] = DPP_I(n, 0x125);  srcv[6] = DPP_I(n, 0x126);
    srcv[7] = DPP_I(n, 0x127);

    int rsrc[8];
#pragma unroll
    for (int r = 0; r < 8; ++r) rsrc[r] = (srcv[r] & 7) ^ 7;

    if ((int)blockIdx.x < ABLK) {
        // ---------------- forward: t in [0, H), blocks t>>3 ----------------
        const int b4   = blockIdx.x * 4;
        const int b    = min(b4 + grp, B - 1);
        const int len  = lengths[b];
        const int lenA = min(len, H);
        const int l0 = lengths[min(b4 + 0, B - 1)];
        const int l1 = lengths[min(b4 + 1, B - 1)];
        const int l2 = lengths[min(b4 + 2, B - 1)];
        const int l3 = lengths[min(b4 + 3, B - 1)];
        const int HA = min(max(max(l0, l1), max(l2, l3)), H);
        const int blocksA = H >> 3;

        float trowR[8];
#pragma unroll
        for (int r = 0; r < 8; ++r)
            trowR[r] = trans[m * TAGS + (srcv[r] & 7)];

        const float* fb = feats + (size_t)b * T * TAGS + m;
        uint8_t* bpa_l = bpA + (size_t)b * blocksA * 32 + ((n >> 1) & 3) * 8;
        const bool stl = (n < 8) && !odd;

        float fv = trans[m * TAGS + START_TAG] + fb[0];   // t=0 closed form

#define KLEAF_A(r, ctrl) { \
        int rot_ = DPP_I(__float_as_int(fv), (ctrl)); \
        float lv_ = __int_as_float(rot_) + trowR[r]; \
        k##r = __int_as_float((__float_as_int(lv_) & ~7) | rsrc[r]); }

#define STEP_A(TI, FEAT, ACCST) { \
        const int t_ = (TI); \
        float k0, k1, k2, k3, k4, k5, k6, k7; \
        { float lv_ = fv + trowR[0]; \
          k0 = __int_as_float((__float_as_int(lv_) & ~7) | rsrc[0]); } \
        KLEAF_A(1, 0x121) KLEAF_A(2, 0x122) KLEAF_A(3, 0x123) \
        KLEAF_A(4, 0x124) KLEAF_A(5, 0x125) KLEAF_A(6, 0x126) \
        KLEAF_A(7, 0x127) \
        const float p1_ = maxf3(k0, k1, k2); \
        const float p2_ = maxf3(k3, k4, k5); \
        const float p3_ = maxf3(k6, k7, p1_); \
        const float mm_ = fmaxf(p2_, p3_); \
        const int idx_  = (__float_as_int(mm_) & 7) ^ 7; \
        const int pidx_ = DPP_I(idx_, 0xB1); \
        const uint32_t byte_ = (uint32_t)(odd ? (pidx_ | (idx_ << 4)) \
                                              : (idx_ | (pidx_ << 4))); \
        ACCST; \
        const float fvn_ = mm_ + (FEAT); \
        fv = ((unsigned)(t_ - 1) < (unsigned)(lenA - 1)) ? fvn_ : fv; }

#define PH_A(USE, LD, T0) { \
        GLOAD8(LD, fb + (size_t)min((T0) + 16, T - 8) * TAGS); \
        WAITP \
        uint32_t accl, acch; \
        STEP_A((T0) + 0, USE[0], accl = byte_) \
        STEP_A((T0) + 1, USE[1], accl |= byte_ << 8) \
        STEP_A((T0) + 2, USE[2], accl |= byte_ << 16) \
        STEP_A((T0) + 3, USE[3], accl |= byte_ << 24) \
        STEP_A((T0) + 4, USE[4], acch = byte_) \
        STEP_A((T0) + 5, USE[5], acch |= byte_ << 8) \
        STEP_A((T0) + 6, USE[6], acch |= byte_ << 16) \
        STEP_A((T0) + 7, USE[7], acch |= byte_ << 24) \
        if ((T0) < H) { \
            if (stl) *(uint2*)(bpa_l + (size_t)((T0) >> 3) * 32) \
                         = make_uint2(accl, acch); } }

        PINFENCE
        float xb[8], yb[8], zb[8];
        GLOAD8(xb, fb);
        GLOAD8(yb, fb + (size_t)min(8, T - 8) * TAGS);
        if (n < 8) *(volatile float*)(fvAo + (size_t)b * 8 + m) = 0.0f; // vmcnt dummy

        for (int t0 = 0; t0 < HA; t0 += 24) {
            PH_A(xb, zb, t0)
            PH_A(yb, xb, t0 + 8)
            PH_A(zb, yb, t0 + 16)
        }
#undef KLEAF_A
#undef STEP_A
#undef PH_A

        if (n < 8)
            fvAo[(size_t)b * 8 + m] = fv;
    } else {
        // ---------------- backward: t in [T-2 .. H-1] ----------------
        const int c4   = (blockIdx.x - ABLK) * 4;
        const int b    = min(c4 + grp, B - 1);
        const int len  = lengths[b];
        const int lenm1 = len - 1;           // step t active iff t < len-1
        const int l0 = lengths[min(c4 + 0, B - 1)];
        const int l1 = lengths[min(c4 + 1, B - 1)];
        const int l2 = lengths[min(c4 + 2, B - 1)];
        const int l3 = lengths[min(c4 + 3, B - 1)];
        const int maxlen = max(max(l0, l1), max(l2, l3));

        const int ktop = (maxlen > H) ? min(NCpad - 1, (maxlen - H - 1) >> 3) : -1;
        const int k0 = ((ktop + 3) / 3) * 3 - 1;   // round up to ==2 (mod 3)

        float trowC[8];
#pragma unroll
        for (int r = 0; r < 8; ++r)
            trowC[r] = trans[(srcv[r] & 7) * TAGS + m];

        float h = trans[STOP_TAG * TAGS + m];   // init at t = len-1
        const float* fb = feats + (size_t)b * T * TAGS + m;
        uint8_t* bpc_l = bpC + (size_t)b * NCpad * 32 + ((n >> 1) & 3) * 8;
        const bool stl = (n < 8) && !odd;

#define KLEAF_C(r, ctrl) { \
        int rot_ = DPP_I(__float_as_int(e_), (ctrl)); \
        float lv_ = __int_as_float(rot_) + trowC[r]; \
        k##r = __int_as_float((__float_as_int(lv_) & ~7) | rsrc[r]); }

#define STEP_C(K, J, FEAT, ACCST) { \
        const int t_ = H - 1 + 8 * (K) + (J); \
        const float e_ = h + (FEAT); \
        float k0, k1, k2, k3, k4, k5, k6, k7; \
        { float lv_ = e_ + trowC[0]; \
          k0 = __int_as_float((__float_as_int(lv_) & ~7) | rsrc[0]); } \
        KLEAF_C(1, 0x121) KLEAF_C(2, 0x122) KLEAF_C(3, 0x123) \
        KLEAF_C(4, 0x124) KLEAF_C(5, 0x125) KLEAF_C(6, 0x126) \
        KLEAF_C(7, 0x127) \
        const float p1_ = maxf3(k0, k1, k2); \
        const float p2_ = maxf3(k3, k4, k5); \
        const float p3_ = maxf3(k6, k7, p1_); \
        const float mm_ = fmaxf(p2_, p3_); \
        const int idx_  = (__float_as_int(mm_) & 7) ^ 7; \
        const int pidx_ = DPP_I(idx_, 0xB1); \
        const uint32_t byte_ = (uint32_t)(odd ? (pidx_ | (idx_ << 4)) \
                                              : (idx_ | (pidx_ << 4))); \
        ACCST; \
        h = (t_ < lenm1) ? mm_ : h; }

#define PH_C(USE, LD, K) { \
        GLOAD8X(LD, fb, H + 8 * ((K) - 2)) \
        WAITP \
        uint32_t accl, acch; \
        STEP_C(K, 7, USE[7], acch = byte_ << 24) \
        STEP_C(K, 6, USE[6], acch |= byte_ << 16) \
        STEP_C(K, 5, USE[5], acch |= byte_ << 8) \
        STEP_C(K, 4, USE[4], acch |= byte_) \
        STEP_C(K, 3, USE[3], accl = byte_ << 24) \
        STEP_C(K, 2, USE[2], accl |= byte_ << 16) \
        STEP_C(K, 1, USE[1], accl |= byte_ << 8) \
        STEP_C(K, 0, USE[0], accl |= byte_) \
        if (stl) *(uint2*)(bpc_l + (size_t)(K) * 32) = make_uint2(accl, acch); }

        PINFENCE
        float xb[8], yb[8], zb[8];
        GLOAD8X(xb, fb, H + 8 * k0)
        GLOAD8X(yb, fb, H + 8 * (k0 - 1))
        if (n < 8) *(volatile float*)(hws + (size_t)b * 8 + m) = 0.0f; // vmcnt dummy

        for (int k = k0; k >= 0; k -= 3) {   // k0 == 2 (mod 3)
            PH_C(xb, zb, k)
            PH_C(yb, xb, k - 1)
            PH_C(zb, yb, k - 2)
        }
#undef KLEAF_C
#undef STEP_C
#undef PH_C

        if (n < 8)
            hws[(size_t)b * 8 + m] = h;      // h at t = H-1
    }
}

// ===========================================================================
// K2: seam compose + two register-pinned 4-deep-pipelined walks.
// nibble chase from named v4i registers (dword (tag&6)+(j>>2), byte j&3,
// nibble tag&1). Steady wait vmcnt(12) = 3x(2 stores + 2 loads); peel
// {6,8,10,12}. blocksA and NCu must be multiples of 4 (guarded in launch).
// ===========================================================================
#define CH_(QA, QB, J) { \
    const uint32_t sA_ = (tag & 2) ? (uint32_t)QA[2 + ((J) >> 2)] \
                                   : (uint32_t)QA[(J) >> 2]; \
    const uint32_t sB_ = (tag & 2) ? (uint32_t)QB[2 + ((J) >> 2)] \
                                   : (uint32_t)QB[(J) >> 2]; \
    const uint32_t sel_ = (tag & 4) ? sB_ : sA_; \
    chv_ = (int)((sel_ >> (8 * ((J) & 3) + 4 * (tag & 1))) & 7); }

#define AITER(K, QA, QB, VMC) { \
    asm volatile("s_waitcnt vmcnt(" #VMC ")" ::: "memory"); \
    __builtin_amdgcn_sched_barrier(0); \
    const int k_ = (K); \
    float bufv[8]; \
    _Pragma("unroll") \
    for (int u = 7; u >= 0; --u) { \
        const int t_ = 8 * k_ + u; \
        const bool act_ = t_ < lenA; \
        bufv[u] = act_ ? (float)tag : 0.0f; \
        int chv_; CH_(QA, QB, u) \
        tag = (act_ && t_ >= 1) ? chv_ : tag; \
    } \
    float4* o4_ = (float4*)(orow + 8 * k_); \
    o4_[0] = make_float4(bufv[0], bufv[1], bufv[2], bufv[3]); \
    o4_[1] = make_float4(bufv[4], bufv[5], bufv[6], bufv[7]); \
    const int kn_ = (k_ - 4 < 0) ? 0 : (k_ - 4); \
    GLOADQ(QA, ab8 + (size_t)kn_ * 32); \
    GLOADQ(QB, ab8 + (size_t)kn_ * 32 + 16); }

#define CITER(K, QA, QB, VMC) { \
    asm volatile("s_waitcnt vmcnt(" #VMC ")" ::: "memory"); \
    __builtin_amdgcn_sched_barrier(0); \
    const int k_ = (K); \
    float bufv[8]; \
    _Pragma("unroll") \
    for (int j = 0; j < 8; ++j) { \
        const int t_ = H - 1 + 8 * k_ + j; \
        const bool act_ = t_ < len - 1; \
        int chv_; CH_(QA, QB, j) \
        tag = act_ ? chv_ : tag; \
        bufv[j] = act_ ? (float)tag : 0.0f; \
    } \
    const int p0_ = H + 8 * k_; \
    if (p0_ + 7 < T) { \
        float4* o4_ = (float4*)(orow + p0_); \
        o4_[0] = make_float4(bufv[0], bufv[1], bufv[2], bufv[3]); \
        o4_[1] = make_float4(bufv[4], bufv[5], bufv[6], bufv[7]); \
    } else { \
        _Pragma("unroll") \
        for (int j = 0; j < 8; ++j) \
            if (p0_ + j < T) orow[p0_ + j] = bufv[j]; \
    } \
    const int kn_ = (k_ + 4 >= NCu) ? (NCu - 1) : (k_ + 4); \
    GLOADQ(QA, cb8 + (size_t)kn_ * 32); \
    GLOADQ(QB, cb8 + (size_t)kn_ * 32 + 16); }

__global__ __launch_bounds__(64, 1) void crf_fb_bt(
    const int*     __restrict__ lengths,
    const uint8_t* __restrict__ bpA,
    const uint8_t* __restrict__ bpC,
    const float*   __restrict__ fvA,
    const float*   __restrict__ hws,
    float*         __restrict__ out_scores,
    float*         __restrict__ out_path,
    int B, int T, int H, int NCpad)
{
    const int rb = (B + 63) >> 6;
    const bool roleA = ((int)blockIdx.x < rb);
    const int s = (roleA ? (int)blockIdx.x : (int)blockIdx.x - rb) * 64 + threadIdx.x;
    if (s >= B) return;
    const int len = lengths[s];
    const int blocksA = H >> 3;
    const int NCu = (T - H + 7) >> 3;

    // compose: score = max_n(fv[n] + h[n]); b* = first-index argmax (exact
    // reference terminal when len <= H since h == STOP row then).
    float fa[8], hh[8];
    {
        const float4* f4 = (const float4*)(fvA + (size_t)s * 8);
        float4 a = f4[0], c = f4[1];
        fa[0]=a.x; fa[1]=a.y; fa[2]=a.z; fa[3]=a.w;
        fa[4]=c.x; fa[5]=c.y; fa[6]=c.z; fa[7]=c.w;
        const float4* h4 = (const float4*)(hws + (size_t)s * 8);
        float4 d = h4[0], e = h4[1];
        hh[0]=d.x; hh[1]=d.y; hh[2]=d.z; hh[3]=d.w;
        hh[4]=e.x; hh[5]=e.y; hh[6]=e.z; hh[7]=e.w;
    }
    float best = fa[0] + hh[0];
    int bstar = 0;
#pragma unroll
    for (int nn = 1; nn < 8; ++nn) {
        const float v = fa[nn] + hh[nn];
        if (v > best) { best = v; bstar = nn; }
    }

    float* orow = out_path + (size_t)s * T;
    int tag = bstar;
    v4i Q0a, Q0b, Q1a, Q1b, Q2a, Q2b, Q3a, Q3b;

    if (roleA) {
        const int lenA = min(len, H);
        const uint8_t* ab8 = bpA + (size_t)s * blocksA * 32;
        const int kt = blocksA - 1;          // kt % 4 == 3 (guarded)
        GLOADQ(Q3a, ab8 + (size_t)kt * 32);       GLOADQ(Q3b, ab8 + (size_t)kt * 32 + 16);
        GLOADQ(Q2a, ab8 + (size_t)(kt - 1) * 32); GLOADQ(Q2b, ab8 + (size_t)(kt - 1) * 32 + 16);
        GLOADQ(Q1a, ab8 + (size_t)(kt - 2) * 32); GLOADQ(Q1b, ab8 + (size_t)(kt - 2) * 32 + 16);
        GLOADQ(Q0a, ab8 + (size_t)(kt - 3) * 32); GLOADQ(Q0b, ab8 + (size_t)(kt - 3) * 32 + 16);
        AITER(kt,     Q3a, Q3b, 6)
        AITER(kt - 1, Q2a, Q2b, 8)
        AITER(kt - 2, Q1a, Q1b, 10)
        AITER(kt - 3, Q0a, Q0b, 12)
        for (int k = kt - 4; k >= 3; k -= 4) {
            AITER(k,     Q3a, Q3b, 12)
            AITER(k - 1, Q2a, Q2b, 12)
            AITER(k - 2, Q1a, Q1b, 12)
            AITER(k - 3, Q0a, Q0b, 12)
        }
    } else {
        out_scores[s] = best;                // before loads: oldest vmem op
        const uint8_t* cb8 = bpC + (size_t)s * NCpad * 32;
        GLOADQ(Q0a, cb8);                    GLOADQ(Q0b, cb8 + 16);
        GLOADQ(Q1a, cb8 + 32);               GLOADQ(Q1b, cb8 + 48);
        GLOADQ(Q2a, cb8 + 64);               GLOADQ(Q2b, cb8 + 80);
        GLOADQ(Q3a, cb8 + 96);               GLOADQ(Q3b, cb8 + 112);
        CITER(0, Q0a, Q0b, 6)
        CITER(1, Q1a, Q1b, 8)
        CITER(2, Q2a, Q2b, 10)
        CITER(3, Q3a, Q3b, 12)
        for (int k = 4; k + 3 < NCu; k += 4) {
            CITER(k,     Q0a, Q0b, 12)
            CITER(k + 1, Q1a, Q1b, 12)
            CITER(k + 2, Q2a, Q2b, 12)
            CITER(k + 3, Q3a, Q3b, 12)
        }
    }
}

// ===========================================================================
// Fallback (ws too small / odd shapes): R8 fused kernel verbatim.
// ===========================================================================
__global__ __launch_bounds__(64, 1) void crf_fused_small(
    const float* __restrict__ feats,
    const int*   __restrict__ lengths,
    const float* __restrict__ trans,
    float*       __restrict__ out_scores,
    float*       __restrict__ out_path,
    uint8_t*     __restrict__ bp4,
    int B, int T)
{
    const int lane = threadIdx.x & 63;
    const int grp  = lane >> 4;
    const int n    = lane & 15;
    const int m    = n & 7;
    const bool odd = (n & 1);
    const int b4   = blockIdx.x * 4;
    const int b    = min(b4 + grp, B - 1);

    const int len = lengths[b];
    const int l0 = lengths[min(b4 + 0, B - 1)];
    const int l1 = lengths[min(b4 + 1, B - 1)];
    const int l2 = lengths[min(b4 + 2, B - 1)];
    const int l3 = lengths[min(b4 + 3, B - 1)];
    const int maxlen = max(max(l0, l1), max(l2, l3));

    int srcv[8];
    srcv[0] = n;
    srcv[1] = DPP_I(n, 0x121);  srcv[2] = DPP_I(n, 0x122);
    srcv[3] = DPP_I(n, 0x123);  srcv[4] = DPP_I(n, 0x124);
    srcv[5] = DPP_I(n, 0x125);  srcv[6] = DPP_I(n, 0x126);
    srcv[7] = DPP_I(n, 0x127);

    float trowR[8];
    int   rsrc[8];
#pragma unroll
    for (int r = 0; r < 8; ++r) {
        const int sq = srcv[r] & 7;
        trowR[r] = trans[m * TAGS + sq];
        rsrc[r]  = sq ^ 7;
    }

    const float* fb = feats + (size_t)b * T * TAGS + m;
    uint8_t* bpb = bp4 + (size_t)b * T * 4 + (n >> 1);
    const bool store_lane = (n < 8) && !odd;

    float fv = trans[m * TAGS + START_TAG] + fb[0];

#define KLEAF_S(r, ctrl) { \
        int rot_ = DPP_I(__float_as_int(fv), (ctrl)); \
        float lv_ = __int_as_float(rot_) + trowR[r]; \
        k##r = __int_as_float((__float_as_int(lv_) & ~7) | rsrc[r]); }

#define STEP_S(TI, FEAT) { \
        const int t_ = (TI); \
        float k0, k1, k2, k3, k4, k5, k6, k7; \
        { float lv_ = fv + trowR[0]; \
          k0 = __int_as_float((__float_as_int(lv_) & ~7) | rsrc[0]); } \
        KLEAF_S(1, 0x121) KLEAF_S(2, 0x122) KLEAF_S(3, 0x123) \
        KLEAF_S(4, 0x124) KLEAF_S(5, 0x125) KLEAF_S(6, 0x126) \
        KLEAF_S(7, 0x127) \
        const float p1_ = maxf3(k0, k1, k2); \
        const float p2_ = maxf3(k3, k4, k5); \
        const float p3_ = maxf3(k6, k7, p1_); \
        const float mm_ = fmaxf(p2_, p3_); \
        const int   idx_  = (__float_as_int(mm_) & 7) ^ 7; \
        const int   pidx_ = DPP_I(idx_, 0xB1); \
        const int   lo_   = odd ? pidx_ : idx_; \
        const int   hi_   = odd ? idx_ : pidx_; \
        const float fvn_  = mm_ + (FEAT); \
        fv = (t_ < len) ? fvn_ : fv; \
        if (t_ < T) { \
            if (store_lane) \
                bpb[(size_t)t_ * 4] = (uint8_t)(lo_ | (hi_ << 4)); \
        } }

    float fc[8], fn[8];
#pragma unroll
    for (int i = 0; i < 8; ++i)
        fc[i] = fb[(size_t)min(1 + i, T - 1) * TAGS];

    for (int t0 = 1; t0 < maxlen; t0 += 8) {
#pragma unroll
        for (int i = 0; i < 8; ++i)
            fn[i] = fb[(size_t)min(t0 + 8 + i, T - 1) * TAGS];

        STEP_S(t0 + 0, fc[0]) STEP_S(t0 + 1, fc[1])
        STEP_S(t0 + 2, fc[2]) STEP_S(t0 + 3, fc[3])
        STEP_S(t0 + 4, fc[4]) STEP_S(t0 + 5, fc[5])
        STEP_S(t0 + 6, fc[6]) STEP_S(t0 + 7, fc[7])

#pragma unroll
        for (int i = 0; i < 8; ++i) fc[i] = fn[i];
    }
#undef KLEAF_S
#undef STEP_S

    const float term = fv + trans[STOP_TAG * TAGS + m];
    float kk = __int_as_float((__float_as_int(term) & ~7) | (m ^ 7));
    kk = fmaxf(kk, __int_as_float(DPP_I(__float_as_int(kk), 0x124)));
    kk = fmaxf(kk, __int_as_float(DPP_I(__float_as_int(kk), 0x122)));
    kk = fmaxf(kk, __int_as_float(DPP_I(__float_as_int(kk), 0x121)));
    int tag = (__float_as_int(kk) & 7) ^ 7;

    if (n == 0)
        out_scores[b] = kk;

    __builtin_amdgcn_s_waitcnt(0);
    __builtin_amdgcn_sched_barrier(0);

    if (n == 0) {
        const uint32_t* rw = (const uint32_t*)(bp4 + (size_t)b * T * 4);
        float* orow = out_path + (size_t)b * T;
        const int NB = (T + 15) / 16;
        uint32_t wA[16], wB[16];

        auto loadblk = [&](int bi, uint32_t* w) {
            if (bi < 0) return;
#pragma unroll
            for (int j = 0; j < 4; ++j) {
                const int tb = min(bi * 16 + 4 * j, T - 4);
                *(uint4*)&w[4 * j] = *(const uint4*)&rw[tb];
            }
        };
        auto compblk = [&](int bi, uint32_t* w) {
            float buf[16];
#pragma unroll
            for (int u = 15; u >= 0; --u) {
                const int t = bi * 16 + u;
                if (t < T) {
                    const bool act = t < len;
                    buf[u] = act ? (float)tag : 0.0f;
                    if (act) tag = (int)((w[u] >> (4 * tag)) & 15);
                }
            }
#pragma unroll
            for (int j = 0; j < 16; j += 4) {
                const int t = bi * 16 + j;
                if (t + 3 < T)
                    *(float4*)(orow + t) = make_float4(buf[j], buf[j+1], buf[j+2], buf[j+3]);
            }
        };

        int bi = NB - 1;
        loadblk(bi, wA);
        loadblk(bi - 1, wB);
        for (; bi >= 0; bi -= 2) {
            compblk(bi, wA);
            loadblk(bi - 2, wA);
            if (bi - 1 >= 0) compblk(bi - 1, wB);
            loadblk(bi - 3, wB);
        }
    }
}

extern "C" void kernel_launch(void* const* d_in, const int* in_sizes, int n_in,
                              void* d_out, int out_size, void* d_ws, size_t ws_size,
                              hipStream_t stream)
{
    const float* feats   = (const float*)d_in[0];
    const int*   lengths = (const int*)d_in[1];
    const float* trans   = (const float*)d_in[2];
    const int B = in_sizes[1];
    const int T = in_sizes[0] / (B * TAGS);

    float* out_scores = (float*)d_out;       // [B]
    float* out_path   = (float*)d_out + B;   // [B, T] tags as floats

    const int H = ((T / 2) + 15) & ~15;      // seam, multiple of 16
    const int blocksA = H >> 3;
    const int NCu = (T - H + 7) >> 3;
    const int NCpad = ((NCu + 3) / 3) * 3;   // K1-C writes up to block NCpad-1

    const size_t szA = (size_t)B * blocksA * 32;
    const size_t szC = (size_t)B * NCpad * 32;
    const size_t need = szA + szC + (size_t)B * 64;

    const bool ok = (H >= 32) && (T > H + 1) && ((T & 3) == 0) && ((B & 3) == 0)
                    && ((blocksA & 3) == 0) && ((NCu & 3) == 0)
                    && (blocksA >= 8) && (NCu >= 8) && (need <= ws_size);

    if (ok) {
        uint8_t* bpA  = (uint8_t*)d_ws;
        uint8_t* bpC  = bpA + szA;
        float*   fvAo = (float*)(bpC + szC);
        float*   hws  = fvAo + (size_t)B * 8;
        const int ABLK = B / 4;

        crf_fb_fwd<<<2 * ABLK, 64, 0, stream>>>(
            feats, lengths, trans, bpA, bpC, fvAo, hws, B, T, H, ABLK, NCpad);

        const int rb = (B + 63) >> 6;
        crf_fb_bt<<<2 * rb, 64, 0, stream>>>(
            lengths, bpA, bpC, fvAo, hws, out_scores, out_path, B, T, H, NCpad);
    } else {
        uint8_t* bp4 = (uint8_t*)d_ws;       // [B][T] 4B words
        crf_fused_small<<<(B + 3) / 4, 64, 0, stream>>>(
            feats, lengths, trans, out_scores, out_path, bp4, B, T);
    }
}

// Round 16
// 68.399 us; speedup vs baseline: 1.7970x; 1.0839x over previous
//
#include <hip/hip_runtime.h>
#include <stdint.h>

#define TAGS 10
#define START_TAG 8
#define STOP_TAG 9
#define NEGV (-10000.0f)

// DPP within 16-lane rows: ROW_ROR:r = 0x120+r, QUAD_PERM[1,0,3,2] = 0xB1.
#define DPP_I(x, ctrl) __builtin_amdgcn_update_dpp(0, (x), (ctrl), 0xF, 0xF, true)

typedef int v4i __attribute__((ext_vector_type(4)));

__device__ __forceinline__ float maxf3(float a, float b, float c) {
    return fmaxf(fmaxf(a, b), c);   // folds to v_max3_f32
}

// Inline-asm loads: structurally pinned in VGPRs (R14 lesson: lambda refs
// demote ping-pong buffers to LDS spill slots).
#define GLOADI(dst, base, OFF) \
    asm volatile("global_load_dword %0, %1, off offset:" #OFF \
                 : "=v"(dst) : "v"(base))
#define GLOADQ(dst, addr) \
    asm volatile("global_load_dwordx4 %0, %1, off" \
                 : "=v"(dst) : "v"((const void*)(addr)) : "memory")
#define GLOAD8(BUF, BASE) { \
    const float* gb_ = (BASE); \
    GLOADI(BUF[0], gb_, 0);   GLOADI(BUF[1], gb_, 40); \
    GLOADI(BUF[2], gb_, 80);  GLOADI(BUF[3], gb_, 120); \
    GLOADI(BUF[4], gb_, 160); GLOADI(BUF[5], gb_, 200); \
    GLOADI(BUF[6], gb_, 240); GLOADI(BUF[7], gb_, 280); }
#define GLOAD8X(BUF, FB, TB) { \
    GLOADI(BUF[0], (FB) + (size_t)min(max((TB) + 0, 0), T - 1) * TAGS, 0); \
    GLOADI(BUF[1], (FB) + (size_t)min(max((TB) + 1, 0), T - 1) * TAGS, 0); \
    GLOADI(BUF[2], (FB) + (size_t)min(max((TB) + 2, 0), T - 1) * TAGS, 0); \
    GLOADI(BUF[3], (FB) + (size_t)min(max((TB) + 3, 0), T - 1) * TAGS, 0); \
    GLOADI(BUF[4], (FB) + (size_t)min(max((TB) + 4, 0), T - 1) * TAGS, 0); \
    GLOADI(BUF[5], (FB) + (size_t)min(max((TB) + 5, 0), T - 1) * TAGS, 0); \
    GLOADI(BUF[6], (FB) + (size_t)min(max((TB) + 6, 0), T - 1) * TAGS, 0); \
    GLOADI(BUF[7], (FB) + (size_t)min(max((TB) + 7, 0), T - 1) * TAGS, 0); }
#define WAITP { asm volatile("s_waitcnt vmcnt(17)" ::: "memory"); \
                __builtin_amdgcn_sched_barrier(0); }
#define PINFENCE __builtin_amdgcn_sched_barrier(0);

// ===========================================================================
// K0: one-block LDS counting sort of sequence indices by length (ascending).
// Sort order affects only WAVE GROUPING in K1 (load balance), never results:
// frozen steps are identity, unchased bp bytes are dead. The atomic scatter's
// within-bucket order is nondeterministic but output-invariant.
// ===========================================================================
__global__ __launch_bounds__(1024) void crf_sort(
    const int* __restrict__ lengths, int* __restrict__ ord, int B)
{
    __shared__ int hist[1024];
    __shared__ int offs[1024];
    const int tid = threadIdx.x;
    hist[tid] = 0;
    __syncthreads();
    for (int i = tid; i < B; i += 1024)
        atomicAdd(&hist[min(max(lengths[i], 0), 1023)], 1);
    __syncthreads();
    offs[tid] = hist[tid];
    __syncthreads();
    for (int off = 1; off < 1024; off <<= 1) {       // Hillis-Steele inclusive
        int v = (tid >= off) ? offs[tid - off] : 0;
        __syncthreads();
        offs[tid] += v;
        __syncthreads();
    }
    hist[tid] = offs[tid] - hist[tid];               // exclusive base
    __syncthreads();
    for (int i = tid; i < B; i += 1024) {
        const int p = atomicAdd(&hist[min(max(lengths[i], 0), 1023)], 1);
        ord[p] = i;
    }
}

// ===========================================================================
// K1: 2-way meet-in-the-middle (R15 structure) + sorted grouping.
// A-block g handles sorted seqs ord[4g..4g+4) (wave runtime ~min(len,H));
// C-block g handles MIRRORED group ord[4(ABLK-1-g)..+4) (runtime (len-H)+),
// so every SIMD's A+C work sums to ~const (min(l,H) + (l'-H)+ with l' the
// mirror quantile) — flat load across the machine.
// ===========================================================================
__global__ __launch_bounds__(64, 1) void crf_fb_fwd(
    const float* __restrict__ feats,
    const int*   __restrict__ lengths,
    const float* __restrict__ trans,
    const int*   __restrict__ ord,
    uint8_t*     __restrict__ bpA,
    uint8_t*     __restrict__ bpC,
    float*       __restrict__ fvAo,
    float*       __restrict__ hws,
    int B, int T, int H, int ABLK, int NCpad)
{
    const int lane = threadIdx.x & 63;
    const int grp  = lane >> 4;
    const int n    = lane & 15;
    const int m    = n & 7;
    const bool odd = (n & 1);

    int srcv[8];
    srcv[0] = n;
    srcv[1] = DPP_I(n, 0x121);  srcv[2] = DPP_I(n, 0x122);
    srcv[3] = DPP_I(n, 0x123);  srcv[4] = DPP_I(n, 0x124);
    srcv[5] = DPP_I(n, 0x125);  srcv[6] = DPP_I(n, 0x126);
    srcv[7] = DPP_I(n, 0x127);

    int rsrc[8];
#pragma unroll
    for (int r = 0; r < 8; ++r) rsrc[r] = (srcv[r] & 7) ^ 7;

    if ((int)blockIdx.x < ABLK) {
        // ---------------- forward: t in [0, H), blocks t>>3 ----------------
        const int b4   = blockIdx.x * 4;
        const int b    = ord[b4 + grp];
        const int len  = lengths[b];
        const int lenA = min(len, H);
        const int l0 = lengths[ord[b4 + 0]];
        const int l1 = lengths[ord[b4 + 1]];
        const int l2 = lengths[ord[b4 + 2]];
        const int l3 = lengths[ord[b4 + 3]];
        const int HA = min(max(max(l0, l1), max(l2, l3)), H);
        const int blocksA = H >> 3;

        float trowR[8];
#pragma unroll
        for (int r = 0; r < 8; ++r)
            trowR[r] = trans[m * TAGS + (srcv[r] & 7)];

        const float* fb = feats + (size_t)b * T * TAGS + m;
        uint8_t* bpa_l = bpA + (size_t)b * blocksA * 32 + ((n >> 1) & 3) * 8;
        const bool stl = (n < 8) && !odd;

        float fv = trans[m * TAGS + START_TAG] + fb[0];   // t=0 closed form

#define KLEAF_A(r, ctrl) { \
        int rot_ = DPP_I(__float_as_int(fv), (ctrl)); \
        float lv_ = __int_as_float(rot_) + trowR[r]; \
        k##r = __int_as_float((__float_as_int(lv_) & ~7) | rsrc[r]); }

#define STEP_A(TI, FEAT, ACCST) { \
        const int t_ = (TI); \
        float k0, k1, k2, k3, k4, k5, k6, k7; \
        { float lv_ = fv + trowR[0]; \
          k0 = __int_as_float((__float_as_int(lv_) & ~7) | rsrc[0]); } \
        KLEAF_A(1, 0x121) KLEAF_A(2, 0x122) KLEAF_A(3, 0x123) \
        KLEAF_A(4, 0x124) KLEAF_A(5, 0x125) KLEAF_A(6, 0x126) \
        KLEAF_A(7, 0x127) \
        const float p1_ = maxf3(k0, k1, k2); \
        const float p2_ = maxf3(k3, k4, k5); \
        const float p3_ = maxf3(k6, k7, p1_); \
        const float mm_ = fmaxf(p2_, p3_); \
        const int idx_  = (__float_as_int(mm_) & 7) ^ 7; \
        const int pidx_ = DPP_I(idx_, 0xB1); \
        const uint32_t byte_ = (uint32_t)(odd ? (pidx_ | (idx_ << 4)) \
                                              : (idx_ | (pidx_ << 4))); \
        ACCST; \
        const float fvn_ = mm_ + (FEAT); \
        fv = ((unsigned)(t_ - 1) < (unsigned)(lenA - 1)) ? fvn_ : fv; }

#define PH_A(USE, LD, T0) { \
        GLOAD8(LD, fb + (size_t)min((T0) + 16, T - 8) * TAGS); \
        WAITP \
        uint32_t accl, acch; \
        STEP_A((T0) + 0, USE[0], accl = byte_) \
        STEP_A((T0) + 1, USE[1], accl |= byte_ << 8) \
        STEP_A((T0) + 2, USE[2], accl |= byte_ << 16) \
        STEP_A((T0) + 3, USE[3], accl |= byte_ << 24) \
        STEP_A((T0) + 4, USE[4], acch = byte_) \
        STEP_A((T0) + 5, USE[5], acch |= byte_ << 8) \
        STEP_A((T0) + 6, USE[6], acch |= byte_ << 16) \
        STEP_A((T0) + 7, USE[7], acch |= byte_ << 24) \
        if ((T0) < H) { \
            if (stl) *(uint2*)(bpa_l + (size_t)((T0) >> 3) * 32) \
                         = make_uint2(accl, acch); } }

        PINFENCE
        float xb[8], yb[8], zb[8];
        GLOAD8(xb, fb);
        GLOAD8(yb, fb + (size_t)min(8, T - 8) * TAGS);
        if (n < 8) *(volatile float*)(fvAo + (size_t)b * 8 + m) = 0.0f; // vmcnt dummy

        for (int t0 = 0; t0 < HA; t0 += 24) {
            PH_A(xb, zb, t0)
            PH_A(yb, xb, t0 + 8)
            PH_A(zb, yb, t0 + 16)
        }
#undef KLEAF_A
#undef STEP_A
#undef PH_A

        if (n < 8)
            fvAo[(size_t)b * 8 + m] = fv;
    } else {
        // ---------------- backward: t in [T-2 .. H-1], mirrored group ----------------
        const int g    = blockIdx.x - ABLK;
        const int c4   = (ABLK - 1 - g) * 4;
        const int b    = ord[c4 + grp];
        const int len  = lengths[b];
        const int lenm1 = len - 1;           // step t active iff t < len-1
        const int l0 = lengths[ord[c4 + 0]];
        const int l1 = lengths[ord[c4 + 1]];
        const int l2 = lengths[ord[c4 + 2]];
        const int l3 = lengths[ord[c4 + 3]];
        const int maxlen = max(max(l0, l1), max(l2, l3));

        const int ktop = (maxlen > H) ? min(NCpad - 1, (maxlen - H - 1) >> 3) : -1;
        const int k0 = ((ktop + 3) / 3) * 3 - 1;   // round up to ==2 (mod 3)

        float trowC[8];
#pragma unroll
        for (int r = 0; r < 8; ++r)
            trowC[r] = trans[(srcv[r] & 7) * TAGS + m];

        float h = trans[STOP_TAG * TAGS + m];   // init at t = len-1
        const float* fb = feats + (size_t)b * T * TAGS + m;
        uint8_t* bpc_l = bpC + (size_t)b * NCpad * 32 + ((n >> 1) & 3) * 8;
        const bool stl = (n < 8) && !odd;

#define KLEAF_C(r, ctrl) { \
        int rot_ = DPP_I(__float_as_int(e_), (ctrl)); \
        float lv_ = __int_as_float(rot_) + trowC[r]; \
        k##r = __int_as_float((__float_as_int(lv_) & ~7) | rsrc[r]); }

#define STEP_C(K, J, FEAT, ACCST) { \
        const int t_ = H - 1 + 8 * (K) + (J); \
        const float e_ = h + (FEAT); \
        float k0, k1, k2, k3, k4, k5, k6, k7; \
        { float lv_ = e_ + trowC[0]; \
          k0 = __int_as_float((__float_as_int(lv_) & ~7) | rsrc[0]); } \
        KLEAF_C(1, 0x121) KLEAF_C(2, 0x122) KLEAF_C(3, 0x123) \
        KLEAF_C(4, 0x124) KLEAF_C(5, 0x125) KLEAF_C(6, 0x126) \
        KLEAF_C(7, 0x127) \
        const float p1_ = maxf3(k0, k1, k2); \
        const float p2_ = maxf3(k3, k4, k5); \
        const float p3_ = maxf3(k6, k7, p1_); \
        const float mm_ = fmaxf(p2_, p3_); \
        const int idx_  = (__float_as_int(mm_) & 7) ^ 7; \
        const int pidx_ = DPP_I(idx_, 0xB1); \
        const uint32_t byte_ = (uint32_t)(odd ? (pidx_ | (idx_ << 4)) \
                                              : (idx_ | (pidx_ << 4))); \
        ACCST; \
        h = (t_ < lenm1) ? mm_ : h; }

#define PH_C(USE, LD, K) { \
        GLOAD8X(LD, fb, H + 8 * ((K) - 2)) \
        WAITP \
        uint32_t accl, acch; \
        STEP_C(K, 7, USE[7], acch = byte_ << 24) \
        STEP_C(K, 6, USE[6], acch |= byte_ << 16) \
        STEP_C(K, 5, USE[5], acch |= byte_ << 8) \
        STEP_C(K, 4, USE[4], acch |= byte_) \
        STEP_C(K, 3, USE[3], accl = byte_ << 24) \
        STEP_C(K, 2, USE[2], accl |= byte_ << 16) \
        STEP_C(K, 1, USE[1], accl |= byte_ << 8) \
        STEP_C(K, 0, USE[0], accl |= byte_) \
        if (stl) *(uint2*)(bpc_l + (size_t)(K) * 32) = make_uint2(accl, acch); }

        PINFENCE
        float xb[8], yb[8], zb[8];
        GLOAD8X(xb, fb, H + 8 * k0)
        GLOAD8X(yb, fb, H + 8 * (k0 - 1))
        if (n < 8) *(volatile float*)(hws + (size_t)b * 8 + m) = 0.0f; // vmcnt dummy

        for (int k = k0; k >= 0; k -= 3) {   // k0 == 2 (mod 3)
            PH_C(xb, zb, k)
            PH_C(yb, xb, k - 1)
            PH_C(zb, yb, k - 2)
        }
#undef KLEAF_C
#undef STEP_C
#undef PH_C

        if (n < 8)
            hws[(size_t)b * 8 + m] = h;      // h at t = H-1
    }
}

// ===========================================================================
// K2: seam compose + register-pinned 4-deep-pipelined walks (R15-verified).
// ===========================================================================
#define CH_(QA, QB, J) { \
    const uint32_t sA_ = (tag & 2) ? (uint32_t)QA[2 + ((J) >> 2)] \
                                   : (uint32_t)QA[(J) >> 2]; \
    const uint32_t sB_ = (tag & 2) ? (uint32_t)QB[2 + ((J) >> 2)] \
                                   : (uint32_t)QB[(J) >> 2]; \
    const uint32_t sel_ = (tag & 4) ? sB_ : sA_; \
    chv_ = (int)((sel_ >> (8 * ((J) & 3) + 4 * (tag & 1))) & 7); }

#define AITER(K, QA, QB, VMC) { \
    asm volatile("s_waitcnt vmcnt(" #VMC ")" ::: "memory"); \
    __builtin_amdgcn_sched_barrier(0); \
    const int k_ = (K); \
    float bufv[8]; \
    _Pragma("unroll") \
    for (int u = 7; u >= 0; --u) { \
        const int t_ = 8 * k_ + u; \
        const bool act_ = t_ < lenA; \
        bufv[u] = act_ ? (float)tag : 0.0f; \
        int chv_; CH_(QA, QB, u) \
        tag = (act_ && t_ >= 1) ? chv_ : tag; \
    } \
    float4* o4_ = (float4*)(orow + 8 * k_); \
    o4_[0] = make_float4(bufv[0], bufv[1], bufv[2], bufv[3]); \
    o4_[1] = make_float4(bufv[4], bufv[5], bufv[6], bufv[7]); \
    const int kn_ = (k_ - 4 < 0) ? 0 : (k_ - 4); \
    GLOADQ(QA, ab8 + (size_t)kn_ * 32); \
    GLOADQ(QB, ab8 + (size_t)kn_ * 32 + 16); }

#define CITER(K, QA, QB, VMC) { \
    asm volatile("s_waitcnt vmcnt(" #VMC ")" ::: "memory"); \
    __builtin_amdgcn_sched_barrier(0); \
    const int k_ = (K); \
    float bufv[8]; \
    _Pragma("unroll") \
    for (int j = 0; j < 8; ++j) { \
        const int t_ = H - 1 + 8 * k_ + j; \
        const bool act_ = t_ < len - 1; \
        int chv_; CH_(QA, QB, j) \
        tag = act_ ? chv_ : tag; \
        bufv[j] = act_ ? (float)tag : 0.0f; \
    } \
    const int p0_ = H + 8 * k_; \
    if (p0_ + 7 < T) { \
        float4* o4_ = (float4*)(orow + p0_); \
        o4_[0] = make_float4(bufv[0], bufv[1], bufv[2], bufv[3]); \
        o4_[1] = make_float4(bufv[4], bufv[5], bufv[6], bufv[7]); \
    } else { \
        _Pragma("unroll") \
        for (int j = 0; j < 8; ++j) \
            if (p0_ + j < T) orow[p0_ + j] = bufv[j]; \
    } \
    const int kn_ = (k_ + 4 >= NCu) ? (NCu - 1) : (k_ + 4); \
    GLOADQ(QA, cb8 + (size_t)kn_ * 32); \
    GLOADQ(QB, cb8 + (size_t)kn_ * 32 + 16); }

__global__ __launch_bounds__(64, 1) void crf_fb_bt(
    const int*     __restrict__ lengths,
    const uint8_t* __restrict__ bpA,
    const uint8_t* __restrict__ bpC,
    const float*   __restrict__ fvA,
    const float*   __restrict__ hws,
    float*         __restrict__ out_scores,
    float*         __restrict__ out_path,
    int B, int T, int H, int NCpad)
{
    const int rb = (B + 63) >> 6;
    const bool roleA = ((int)blockIdx.x < rb);
    const int s = (roleA ? (int)blockIdx.x : (int)blockIdx.x - rb) * 64 + threadIdx.x;
    if (s >= B) return;
    const int len = lengths[s];
    const int blocksA = H >> 3;
    const int NCu = (T - H + 7) >> 3;

    float fa[8], hh[8];
    {
        const float4* f4 = (const float4*)(fvA + (size_t)s * 8);
        float4 a = f4[0], c = f4[1];
        fa[0]=a.x; fa[1]=a.y; fa[2]=a.z; fa[3]=a.w;
        fa[4]=c.x; fa[5]=c.y; fa[6]=c.z; fa[7]=c.w;
        const float4* h4 = (const float4*)(hws + (size_t)s * 8);
        float4 d = h4[0], e = h4[1];
        hh[0]=d.x; hh[1]=d.y; hh[2]=d.z; hh[3]=d.w;
        hh[4]=e.x; hh[5]=e.y; hh[6]=e.z; hh[7]=e.w;
    }
    float best = fa[0] + hh[0];
    int bstar = 0;
#pragma unroll
    for (int nn = 1; nn < 8; ++nn) {
        const float v = fa[nn] + hh[nn];
        if (v > best) { best = v; bstar = nn; }
    }

    float* orow = out_path + (size_t)s * T;
    int tag = bstar;
    v4i Q0a, Q0b, Q1a, Q1b, Q2a, Q2b, Q3a, Q3b;

    if (roleA) {
        const int lenA = min(len, H);
        const uint8_t* ab8 = bpA + (size_t)s * blocksA * 32;
        const int kt = blocksA - 1;          // kt % 4 == 3 (guarded)
        GLOADQ(Q3a, ab8 + (size_t)kt * 32);       GLOADQ(Q3b, ab8 + (size_t)kt * 32 + 16);
        GLOADQ(Q2a, ab8 + (size_t)(kt - 1) * 32); GLOADQ(Q2b, ab8 + (size_t)(kt - 1) * 32 + 16);
        GLOADQ(Q1a, ab8 + (size_t)(kt - 2) * 32); GLOADQ(Q1b, ab8 + (size_t)(kt - 2) * 32 + 16);
        GLOADQ(Q0a, ab8 + (size_t)(kt - 3) * 32); GLOADQ(Q0b, ab8 + (size_t)(kt - 3) * 32 + 16);
        AITER(kt,     Q3a, Q3b, 6)
        AITER(kt - 1, Q2a, Q2b, 8)
        AITER(kt - 2, Q1a, Q1b, 10)
        AITER(kt - 3, Q0a, Q0b, 12)
        for (int k = kt - 4; k >= 3; k -= 4) {
            AITER(k,     Q3a, Q3b, 12)
            AITER(k - 1, Q2a, Q2b, 12)
            AITER(k - 2, Q1a, Q1b, 12)
            AITER(k - 3, Q0a, Q0b, 12)
        }
    } else {
        out_scores[s] = best;                // before loads: oldest vmem op
        const uint8_t* cb8 = bpC + (size_t)s * NCpad * 32;
        GLOADQ(Q0a, cb8);                    GLOADQ(Q0b, cb8 + 16);
        GLOADQ(Q1a, cb8 + 32);               GLOADQ(Q1b, cb8 + 48);
        GLOADQ(Q2a, cb8 + 64);               GLOADQ(Q2b, cb8 + 80);
        GLOADQ(Q3a, cb8 + 96);               GLOADQ(Q3b, cb8 + 112);
        CITER(0, Q0a, Q0b, 6)
        CITER(1, Q1a, Q1b, 8)
        CITER(2, Q2a, Q2b, 10)
        CITER(3, Q3a, Q3b, 12)
        for (int k = 4; k + 3 < NCu; k += 4) {
            CITER(k,     Q0a, Q0b, 12)
            CITER(k + 1, Q1a, Q1b, 12)
            CITER(k + 2, Q2a, Q2b, 12)
            CITER(k + 3, Q3a, Q3b, 12)
        }
    }
}

// ===========================================================================
// Fallback (ws too small / odd shapes): R8 fused kernel verbatim.
// ===========================================================================
__global__ __launch_bounds__(64, 1) void crf_fused_small(
    const float* __restrict__ feats,
    const int*   __restrict__ lengths,
    const float* __restrict__ trans,
    float*       __restrict__ out_scores,
    float*       __restrict__ out_path,
    uint8_t*     __restrict__ bp4,
    int B, int T)
{
    const int lane = threadIdx.x & 63;
    const int grp  = lane >> 4;
    const int n    = lane & 15;
    const int m    = n & 7;
    const bool odd = (n & 1);
    const int b4   = blockIdx.x * 4;
    const int b    = min(b4 + grp, B - 1);

    const int len = lengths[b];
    const int l0 = lengths[min(b4 + 0, B - 1)];
    const int l1 = lengths[min(b4 + 1, B - 1)];
    const int l2 = lengths[min(b4 + 2, B - 1)];
    const int l3 = lengths[min(b4 + 3, B - 1)];
    const int maxlen = max(max(l0, l1), max(l2, l3));

    int srcv[8];
    srcv[0] = n;
    srcv[1] = DPP_I(n, 0x121);  srcv[2] = DPP_I(n, 0x122);
    srcv[3] = DPP_I(n, 0x123);  srcv[4] = DPP_I(n, 0x124);
    srcv[5] = DPP_I(n, 0x125);  srcv[6] = DPP_I(n, 0x126);
    srcv[7] = DPP_I(n, 0x127);

    float trowR[8];
    int   rsrc[8];
#pragma unroll
    for (int r = 0; r < 8; ++r) {
        const int sq = srcv[r] & 7;
        trowR[r] = trans[m * TAGS + sq];
        rsrc[r]  = sq ^ 7;
    }

    const float* fb = feats + (size_t)b * T * TAGS + m;
    uint8_t* bpb = bp4 + (size_t)b * T * 4 + (n >> 1);
    const bool store_lane = (n < 8) && !odd;

    float fv = trans[m * TAGS + START_TAG] + fb[0];

#define KLEAF_S(r, ctrl) { \
        int rot_ = DPP_I(__float_as_int(fv), (ctrl)); \
        float lv_ = __int_as_float(rot_) + trowR[r]; \
        k##r = __int_as_float((__float_as_int(lv_) & ~7) | rsrc[r]); }

#define STEP_S(TI, FEAT) { \
        const int t_ = (TI); \
        float k0, k1, k2, k3, k4, k5, k6, k7; \
        { float lv_ = fv + trowR[0]; \
          k0 = __int_as_float((__float_as_int(lv_) & ~7) | rsrc[0]); } \
        KLEAF_S(1, 0x121) KLEAF_S(2, 0x122) KLEAF_S(3, 0x123) \
        KLEAF_S(4, 0x124) KLEAF_S(5, 0x125) KLEAF_S(6, 0x126) \
        KLEAF_S(7, 0x127) \
        const float p1_ = maxf3(k0, k1, k2); \
        const float p2_ = maxf3(k3, k4, k5); \
        const float p3_ = maxf3(k6, k7, p1_); \
        const float mm_ = fmaxf(p2_, p3_); \
        const int   idx_  = (__float_as_int(mm_) & 7) ^ 7; \
        const int   pidx_ = DPP_I(idx_, 0xB1); \
        const int   lo_   = odd ? pidx_ : idx_; \
        const int   hi_   = odd ? idx_ : pidx_; \
        const float fvn_  = mm_ + (FEAT); \
        fv = (t_ < len) ? fvn_ : fv; \
        if (t_ < T) { \
            if (store_lane) \
                bpb[(size_t)t_ * 4] = (uint8_t)(lo_ | (hi_ << 4)); \
        } }

    float fc[8], fn[8];
#pragma unroll
    for (int i = 0; i < 8; ++i)
        fc[i] = fb[(size_t)min(1 + i, T - 1) * TAGS];

    for (int t0 = 1; t0 < maxlen; t0 += 8) {
#pragma unroll
        for (int i = 0; i < 8; ++i)
            fn[i] = fb[(size_t)min(t0 + 8 + i, T - 1) * TAGS];

        STEP_S(t0 + 0, fc[0]) STEP_S(t0 + 1, fc[1])
        STEP_S(t0 + 2, fc[2]) STEP_S(t0 + 3, fc[3])
        STEP_S(t0 + 4, fc[4]) STEP_S(t0 + 5, fc[5])
        STEP_S(t0 + 6, fc[6]) STEP_S(t0 + 7, fc[7])

#pragma unroll
        for (int i = 0; i < 8; ++i) fc[i] = fn[i];
    }
#undef KLEAF_S
#undef STEP_S

    const float term = fv + trans[STOP_TAG * TAGS + m];
    float kk = __int_as_float((__float_as_int(term) & ~7) | (m ^ 7));
    kk = fmaxf(kk, __int_as_float(DPP_I(__float_as_int(kk), 0x124)));
    kk = fmaxf(kk, __int_as_float(DPP_I(__float_as_int(kk), 0x122)));
    kk = fmaxf(kk, __int_as_float(DPP_I(__float_as_int(kk), 0x121)));
    int tag = (__float_as_int(kk) & 7) ^ 7;

    if (n == 0)
        out_scores[b] = kk;

    __builtin_amdgcn_s_waitcnt(0);
    __builtin_amdgcn_sched_barrier(0);

    if (n == 0) {
        const uint32_t* rw = (const uint32_t*)(bp4 + (size_t)b * T * 4);
        float* orow = out_path + (size_t)b * T;
        const int NB = (T + 15) / 16;
        uint32_t wA[16], wB[16];

        auto loadblk = [&](int bi, uint32_t* w) {
            if (bi < 0) return;
#pragma unroll
            for (int j = 0; j < 4; ++j) {
                const int tb = min(bi * 16 + 4 * j, T - 4);
                *(uint4*)&w[4 * j] = *(const uint4*)&rw[tb];
            }
        };
        auto compblk = [&](int bi, uint32_t* w) {
            float buf[16];
#pragma unroll
            for (int u = 15; u >= 0; --u) {
                const int t = bi * 16 + u;
                if (t < T) {
                    const bool act = t < len;
                    buf[u] = act ? (float)tag : 0.0f;
                    if (act) tag = (int)((w[u] >> (4 * tag)) & 15);
                }
            }
#pragma unroll
            for (int j = 0; j < 16; j += 4) {
                const int t = bi * 16 + j;
                if (t + 3 < T)
                    *(float4*)(orow + t) = make_float4(buf[j], buf[j+1], buf[j+2], buf[j+3]);
            }
        };

        int bi = NB - 1;
        loadblk(bi, wA);
        loadblk(bi - 1, wB);
        for (; bi >= 0; bi -= 2) {
            compblk(bi, wA);
            loadblk(bi - 2, wA);
            if (bi - 1 >= 0) compblk(bi - 1, wB);
            loadblk(bi - 3, wB);
        }
    }
}

extern "C" void kernel_launch(void* const* d_in, const int* in_sizes, int n_in,
                              void* d_out, int out_size, void* d_ws, size_t ws_size,
                              hipStream_t stream)
{
    const float* feats   = (const float*)d_in[0];
    const int*   lengths = (const int*)d_in[1];
    const float* trans   = (const float*)d_in[2];
    const int B = in_sizes[1];
    const int T = in_sizes[0] / (B * TAGS);

    float* out_scores = (float*)d_out;       // [B]
    float* out_path   = (float*)d_out + B;   // [B, T] tags as floats

    const int H = ((T / 2) + 15) & ~15;      // seam, multiple of 16
    const int blocksA = H >> 3;
    const int NCu = (T - H + 7) >> 3;
    const int NCpad = ((NCu + 3) / 3) * 3;   // K1-C writes up to block NCpad-1

    const size_t szA = (size_t)B * blocksA * 32;
    const size_t szC = (size_t)B * NCpad * 32;
    const size_t need = szA + szC + (size_t)B * 64 + (size_t)B * 4;

    const bool ok = (H >= 32) && (T > H + 1) && ((T & 3) == 0) && ((B & 3) == 0)
                    && ((blocksA & 3) == 0) && ((NCu & 3) == 0)
                    && (blocksA >= 8) && (NCu >= 8) && (need <= ws_size);

    if (ok) {
        uint8_t* bpA  = (uint8_t*)d_ws;
        uint8_t* bpC  = bpA + szA;
        float*   fvAo = (float*)(bpC + szC);
        float*   hws  = fvAo + (size_t)B * 8;
        int*     ord  = (int*)(hws + (size_t)B * 8);
        const int ABLK = B / 4;

        crf_sort<<<1, 1024, 0, stream>>>(lengths, ord, B);

        crf_fb_fwd<<<2 * ABLK, 64, 0, stream>>>(
            feats, lengths, trans, ord, bpA, bpC, fvAo, hws, B, T, H, ABLK, NCpad);

        const int rb = (B + 63) >> 6;
        crf_fb_bt<<<2 * rb, 64, 0, stream>>>(
            lengths, bpA, bpC, fvAo, hws, out_scores, out_path, B, T, H, NCpad);
    } else {
        uint8_t* bp4 = (uint8_t*)d_ws;       // [B][T] 4B words
        crf_fused_small<<<(B + 3) / 4, 64, 0, stream>>>(
            feats, lengths, trans, out_scores, out_path, bp4, B, T);
    }
}

// Round 17
// 67.155 us; speedup vs baseline: 1.8302x; 1.0185x over previous
//
#include <hip/hip_runtime.h>
#include <stdint.h>

#define TAGS 10
#define START_TAG 8
#define STOP_TAG 9
#define NEGV (-10000.0f)

// DPP within 16-lane rows: ROW_ROR:r = 0x120+r, QUAD_PERM[1,0,3,2] = 0xB1.
#define DPP_I(x, ctrl) __builtin_amdgcn_update_dpp(0, (x), (ctrl), 0xF, 0xF, true)

typedef int v4i __attribute__((ext_vector_type(4)));

__device__ __forceinline__ float maxf3(float a, float b, float c) {
    return fmaxf(fmaxf(a, b), c);   // folds to v_max3_f32
}

// Inline-asm loads: structurally pinned in VGPRs (R14 lesson: lambda refs
// demote ping-pong buffers to LDS spill slots).
#define GLOADI(dst, base, OFF) \
    asm volatile("global_load_dword %0, %1, off offset:" #OFF \
                 : "=v"(dst) : "v"(base))
#define GLOADQ(dst, addr) \
    asm volatile("global_load_dwordx4 %0, %1, off" \
                 : "=v"(dst) : "v"((const void*)(addr)) : "memory")
#define GLOAD8(BUF, BASE) { \
    const float* gb_ = (BASE); \
    GLOADI(BUF[0], gb_, 0);   GLOADI(BUF[1], gb_, 40); \
    GLOADI(BUF[2], gb_, 80);  GLOADI(BUF[3], gb_, 120); \
    GLOADI(BUF[4], gb_, 160); GLOADI(BUF[5], gb_, 200); \
    GLOADI(BUF[6], gb_, 240); GLOADI(BUF[7], gb_, 280); }
#define GLOAD8X(BUF, FB, TB) { \
    GLOADI(BUF[0], (FB) + (size_t)min(max((TB) + 0, 0), T - 1) * TAGS, 0); \
    GLOADI(BUF[1], (FB) + (size_t)min(max((TB) + 1, 0), T - 1) * TAGS, 0); \
    GLOADI(BUF[2], (FB) + (size_t)min(max((TB) + 2, 0), T - 1) * TAGS, 0); \
    GLOADI(BUF[3], (FB) + (size_t)min(max((TB) + 3, 0), T - 1) * TAGS, 0); \
    GLOADI(BUF[4], (FB) + (size_t)min(max((TB) + 4, 0), T - 1) * TAGS, 0); \
    GLOADI(BUF[5], (FB) + (size_t)min(max((TB) + 5, 0), T - 1) * TAGS, 0); \
    GLOADI(BUF[6], (FB) + (size_t)min(max((TB) + 6, 0), T - 1) * TAGS, 0); \
    GLOADI(BUF[7], (FB) + (size_t)min(max((TB) + 7, 0), T - 1) * TAGS, 0); }
#define WAITP { asm volatile("s_waitcnt vmcnt(17)" ::: "memory"); \
                __builtin_amdgcn_sched_barrier(0); }
#define PINFENCE __builtin_amdgcn_sched_barrier(0);

// Fused rotate+add: 7 x v_add_f32_dpp in ONE asm block. The leading s_nop 1
// provides the 2 wait states required between a VALU write of the source
// (fv/e_ cndmask) and a DPP read — the compiler's hazard recognizer cannot
// see into inline asm, so the spacing is provided structurally. Early-clobber
// outputs prevent aliasing with the (still-live) rotated source.
#define DPP7(SRC, TROW) \
    asm("s_nop 1\n" \
        "\tv_add_f32_dpp %0, %7, %8  row_ror:1 row_mask:0xf bank_mask:0xf\n" \
        "\tv_add_f32_dpp %1, %7, %9  row_ror:2 row_mask:0xf bank_mask:0xf\n" \
        "\tv_add_f32_dpp %2, %7, %10 row_ror:3 row_mask:0xf bank_mask:0xf\n" \
        "\tv_add_f32_dpp %3, %7, %11 row_ror:4 row_mask:0xf bank_mask:0xf\n" \
        "\tv_add_f32_dpp %4, %7, %12 row_ror:5 row_mask:0xf bank_mask:0xf\n" \
        "\tv_add_f32_dpp %5, %7, %13 row_ror:6 row_mask:0xf bank_mask:0xf\n" \
        "\tv_add_f32_dpp %6, %7, %14 row_ror:7 row_mask:0xf bank_mask:0xf\n" \
        : "=&v"(l1), "=&v"(l2), "=&v"(l3), "=&v"(l4), \
          "=&v"(l5), "=&v"(l6), "=&v"(l7) \
        : "v"(SRC), "v"(TROW[1]), "v"(TROW[2]), "v"(TROW[3]), \
          "v"(TROW[4]), "v"(TROW[5]), "v"(TROW[6]), "v"(TROW[7]));

// ===========================================================================
// K0: 64-bin (width-16) counting sort by length — single wave-scan, ~4 syncs.
// Bucket order only affects K1 wave grouping (balance slack <= 15 steps),
// never results.
// ===========================================================================
__global__ __launch_bounds__(1024) void crf_sort(
    const int* __restrict__ lengths, int* __restrict__ ord, int B)
{
    __shared__ int hist[64];
    __shared__ int base[64];
    const int tid = threadIdx.x;
    if (tid < 64) hist[tid] = 0;
    __syncthreads();
    for (int i = tid; i < B; i += 1024)
        atomicAdd(&hist[min(lengths[i] >> 4, 63)], 1);
    __syncthreads();
    if (tid < 64) {                       // one wave: shuffle inclusive scan
        const int v = hist[tid];
        int s = v;
#pragma unroll
        for (int off = 1; off < 64; off <<= 1) {
            const int u = __shfl_up(s, off);
            if (tid >= off) s += u;
        }
        base[tid] = s - v;                // exclusive base
    }
    __syncthreads();
    for (int i = tid; i < B; i += 1024) {
        const int p = atomicAdd(&base[min(lengths[i] >> 4, 63)], 1);
        ord[p] = i;
    }
}

// ===========================================================================
// K1: 2-way meet-in-the-middle (R16 structure + DPP-fused adds + lean pack).
// bp nibbles are stored XORed (prev^7 — preserves first-index tie-break via
// max); K2 un-xors on chase. A-block g: sorted seqs ord[4g..); C-block g:
// mirrored group (balance).
// ===========================================================================
__global__ __launch_bounds__(64, 1) void crf_fb_fwd(
    const float* __restrict__ feats,
    const int*   __restrict__ lengths,
    const float* __restrict__ trans,
    const int*   __restrict__ ord,
    uint8_t*     __restrict__ bpA,
    uint8_t*     __restrict__ bpC,
    float*       __restrict__ fvAo,
    float*       __restrict__ hws,
    int B, int T, int H, int ABLK, int NCpad)
{
    const int lane = threadIdx.x & 63;
    const int grp  = lane >> 4;
    const int n    = lane & 15;
    const int m    = n & 7;

    int srcv[8];
    srcv[0] = n;
    srcv[1] = DPP_I(n, 0x121);  srcv[2] = DPP_I(n, 0x122);
    srcv[3] = DPP_I(n, 0x123);  srcv[4] = DPP_I(n, 0x124);
    srcv[5] = DPP_I(n, 0x125);  srcv[6] = DPP_I(n, 0x126);
    srcv[7] = DPP_I(n, 0x127);

    int rsrc[8];
#pragma unroll
    for (int r = 0; r < 8; ++r) rsrc[r] = (srcv[r] & 7) ^ 7;

    if ((int)blockIdx.x < ABLK) {
        // ---------------- forward: t in [0, H), blocks t>>3 ----------------
        const int b4   = blockIdx.x * 4;
        const int b    = ord[b4 + grp];
        const int len  = lengths[b];
        const int lenA = min(len, H);
        const int l0 = lengths[ord[b4 + 0]];
        const int l1_ = lengths[ord[b4 + 1]];
        const int l2_ = lengths[ord[b4 + 2]];
        const int l3_ = lengths[ord[b4 + 3]];
        const int HA = min(max(max(l0, l1_), max(l2_, l3_)), H);
        const int blocksA = H >> 3;

        float trowR[8];
#pragma unroll
        for (int r = 0; r < 8; ++r)
            trowR[r] = trans[m * TAGS + (srcv[r] & 7)];

        const float* fb = feats + (size_t)b * T * TAGS + m;
        uint8_t* bpa_l = bpA + (size_t)b * blocksA * 32 + ((n >> 1) & 3) * 8;
        const bool stl = (n < 8) && !(n & 1);

        float fv = trans[m * TAGS + START_TAG] + fb[0];   // t=0 closed form

#define STEP_A(TI, FEAT, ACCST) { \
        const int t_ = (TI); \
        float l1, l2, l3, l4, l5, l6, l7; \
        DPP7(fv, trowR) \
        float k0; \
        { float lv_ = fv + trowR[0]; \
          k0 = __int_as_float((__float_as_int(lv_) & ~7) | rsrc[0]); } \
        const float k1 = __int_as_float((__float_as_int(l1) & ~7) | rsrc[1]); \
        const float k2 = __int_as_float((__float_as_int(l2) & ~7) | rsrc[2]); \
        const float k3 = __int_as_float((__float_as_int(l3) & ~7) | rsrc[3]); \
        const float k4 = __int_as_float((__float_as_int(l4) & ~7) | rsrc[4]); \
        const float k5 = __int_as_float((__float_as_int(l5) & ~7) | rsrc[5]); \
        const float k6 = __int_as_float((__float_as_int(l6) & ~7) | rsrc[6]); \
        const float k7 = __int_as_float((__float_as_int(l7) & ~7) | rsrc[7]); \
        const float p1_ = maxf3(k0, k1, k2); \
        const float p2_ = maxf3(k3, k4, k5); \
        const float p3_ = maxf3(k6, k7, p1_); \
        const float mm_ = fmaxf(p2_, p3_); \
        const int xidx_ = __float_as_int(mm_) & 7;        /* prev^7 */ \
        const int pidx_ = DPP_I(xidx_, 0xB1); \
        const uint32_t byte_ = (uint32_t)(xidx_ | (pidx_ << 4)); \
        ACCST; \
        const float fvn_ = mm_ + (FEAT); \
        fv = ((unsigned)(t_ - 1) < (unsigned)(lenA - 1)) ? fvn_ : fv; }

#define PH_A(USE, LD, T0) { \
        GLOAD8(LD, fb + (size_t)min((T0) + 16, T - 8) * TAGS); \
        WAITP \
        uint32_t accl, acch; \
        STEP_A((T0) + 0, USE[0], accl = byte_) \
        STEP_A((T0) + 1, USE[1], accl |= byte_ << 8) \
        STEP_A((T0) + 2, USE[2], accl |= byte_ << 16) \
        STEP_A((T0) + 3, USE[3], accl |= byte_ << 24) \
        STEP_A((T0) + 4, USE[4], acch = byte_) \
        STEP_A((T0) + 5, USE[5], acch |= byte_ << 8) \
        STEP_A((T0) + 6, USE[6], acch |= byte_ << 16) \
        STEP_A((T0) + 7, USE[7], acch |= byte_ << 24) \
        if ((T0) < H) { \
            if (stl) *(uint2*)(bpa_l + (size_t)((T0) >> 3) * 32) \
                         = make_uint2(accl, acch); } }

        PINFENCE
        float xb[8], yb[8], zb[8];
        GLOAD8(xb, fb);
        GLOAD8(yb, fb + (size_t)min(8, T - 8) * TAGS);
        if (n < 8) *(volatile float*)(fvAo + (size_t)b * 8 + m) = 0.0f; // vmcnt dummy

        for (int t0 = 0; t0 < HA; t0 += 24) {
            PH_A(xb, zb, t0)
            PH_A(yb, xb, t0 + 8)
            PH_A(zb, yb, t0 + 16)
        }
#undef STEP_A
#undef PH_A

        if (n < 8)
            fvAo[(size_t)b * 8 + m] = fv;
    } else {
        // ---------------- backward: t in [T-2 .. H-1], mirrored group ----------------
        const int g    = blockIdx.x - ABLK;
        const int c4   = (ABLK - 1 - g) * 4;
        const int b    = ord[c4 + grp];
        const int len  = lengths[b];
        const int lenm1 = len - 1;           // step t active iff t < len-1
        const int l0 = lengths[ord[c4 + 0]];
        const int l1_ = lengths[ord[c4 + 1]];
        const int l2_ = lengths[ord[c4 + 2]];
        const int l3_ = lengths[ord[c4 + 3]];
        const int maxlen = max(max(l0, l1_), max(l2_, l3_));

        const int ktop = (maxlen > H) ? min(NCpad - 1, (maxlen - H - 1) >> 3) : -1;
        const int k0i = ((ktop + 3) / 3) * 3 - 1;   // round up to ==2 (mod 3)

        float trowC[8];
#pragma unroll
        for (int r = 0; r < 8; ++r)
            trowC[r] = trans[(srcv[r] & 7) * TAGS + m];

        float h = trans[STOP_TAG * TAGS + m];   // init at t = len-1
        const float* fb = feats + (size_t)b * T * TAGS + m;
        uint8_t* bpc_l = bpC + (size_t)b * NCpad * 32 + ((n >> 1) & 3) * 8;
        const bool stl = (n < 8) && !(n & 1);

#define STEP_C(K, J, FEAT, ACCST) { \
        const int t_ = H - 1 + 8 * (K) + (J); \
        const float e_ = h + (FEAT); \
        float l1, l2, l3, l4, l5, l6, l7; \
        DPP7(e_, trowC) \
        float k0; \
        { float lv_ = e_ + trowC[0]; \
          k0 = __int_as_float((__float_as_int(lv_) & ~7) | rsrc[0]); } \
        const float k1 = __int_as_float((__float_as_int(l1) & ~7) | rsrc[1]); \
        const float k2 = __int_as_float((__float_as_int(l2) & ~7) | rsrc[2]); \
        const float k3 = __int_as_float((__float_as_int(l3) & ~7) | rsrc[3]); \
        const float k4 = __int_as_float((__float_as_int(l4) & ~7) | rsrc[4]); \
        const float k5 = __int_as_float((__float_as_int(l5) & ~7) | rsrc[5]); \
        const float k6 = __int_as_float((__float_as_int(l6) & ~7) | rsrc[6]); \
        const float k7 = __int_as_float((__float_as_int(l7) & ~7) | rsrc[7]); \
        const float p1_ = maxf3(k0, k1, k2); \
        const float p2_ = maxf3(k3, k4, k5); \
        const float p3_ = maxf3(k6, k7, p1_); \
        const float mm_ = fmaxf(p2_, p3_); \
        const int xidx_ = __float_as_int(mm_) & 7;        /* prev^7 */ \
        const int pidx_ = DPP_I(xidx_, 0xB1); \
        const uint32_t byte_ = (uint32_t)(xidx_ | (pidx_ << 4)); \
        ACCST; \
        h = (t_ < lenm1) ? mm_ : h; }

#define PH_C(USE, LD, K) { \
        GLOAD8X(LD, fb, H + 8 * ((K) - 2)) \
        WAITP \
        uint32_t accl, acch; \
        STEP_C(K, 7, USE[7], acch = byte_ << 24) \
        STEP_C(K, 6, USE[6], acch |= byte_ << 16) \
        STEP_C(K, 5, USE[5], acch |= byte_ << 8) \
        STEP_C(K, 4, USE[4], acch |= byte_) \
        STEP_C(K, 3, USE[3], accl = byte_ << 24) \
        STEP_C(K, 2, USE[2], accl |= byte_ << 16) \
        STEP_C(K, 1, USE[1], accl |= byte_ << 8) \
        STEP_C(K, 0, USE[0], accl |= byte_) \
        if (stl) *(uint2*)(bpc_l + (size_t)(K) * 32) = make_uint2(accl, acch); }

        PINFENCE
        float xb[8], yb[8], zb[8];
        GLOAD8X(xb, fb, H + 8 * k0i)
        GLOAD8X(yb, fb, H + 8 * (k0i - 1))
        if (n < 8) *(volatile float*)(hws + (size_t)b * 8 + m) = 0.0f; // vmcnt dummy

        for (int k = k0i; k >= 0; k -= 3) {   // k0i == 2 (mod 3)
            PH_C(xb, zb, k)
            PH_C(yb, xb, k - 1)
            PH_C(zb, yb, k - 2)
        }
#undef STEP_C
#undef PH_C

        if (n < 8)
            hws[(size_t)b * 8 + m] = h;      // h at t = H-1
    }
}

// ===========================================================================
// K2: seam compose + register-pinned 4-deep-pipelined walks (R15-verified).
// Chase un-xors the stored nibble (prev = nibble ^ 7).
// ===========================================================================
#define CH_(QA, QB, J) { \
    const uint32_t sA_ = (tag & 2) ? (uint32_t)QA[2 + ((J) >> 2)] \
                                   : (uint32_t)QA[(J) >> 2]; \
    const uint32_t sB_ = (tag & 2) ? (uint32_t)QB[2 + ((J) >> 2)] \
                                   : (uint32_t)QB[(J) >> 2]; \
    const uint32_t sel_ = (tag & 4) ? sB_ : sA_; \
    chv_ = (int)(((sel_ >> (8 * ((J) & 3) + 4 * (tag & 1))) & 7) ^ 7); }

#define AITER(K, QA, QB, VMC) { \
    asm volatile("s_waitcnt vmcnt(" #VMC ")" ::: "memory"); \
    __builtin_amdgcn_sched_barrier(0); \
    const int k_ = (K); \
    float bufv[8]; \
    _Pragma("unroll") \
    for (int u = 7; u >= 0; --u) { \
        const int t_ = 8 * k_ + u; \
        const bool act_ = t_ < lenA; \
        bufv[u] = act_ ? (float)tag : 0.0f; \
        int chv_; CH_(QA, QB, u) \
        tag = (act_ && t_ >= 1) ? chv_ : tag; \
    } \
    float4* o4_ = (float4*)(orow + 8 * k_); \
    o4_[0] = make_float4(bufv[0], bufv[1], bufv[2], bufv[3]); \
    o4_[1] = make_float4(bufv[4], bufv[5], bufv[6], bufv[7]); \
    const int kn_ = (k_ - 4 < 0) ? 0 : (k_ - 4); \
    GLOADQ(QA, ab8 + (size_t)kn_ * 32); \
    GLOADQ(QB, ab8 + (size_t)kn_ * 32 + 16); }

#define CITER(K, QA, QB, VMC) { \
    asm volatile("s_waitcnt vmcnt(" #VMC ")" ::: "memory"); \
    __builtin_amdgcn_sched_barrier(0); \
    const int k_ = (K); \
    float bufv[8]; \
    _Pragma("unroll") \
    for (int j = 0; j < 8; ++j) { \
        const int t_ = H - 1 + 8 * k_ + j; \
        const bool act_ = t_ < len - 1; \
        int chv_; CH_(QA, QB, j) \
        tag = act_ ? chv_ : tag; \
        bufv[j] = act_ ? (float)tag : 0.0f; \
    } \
    const int p0_ = H + 8 * k_; \
    if (p0_ + 7 < T) { \
        float4* o4_ = (float4*)(orow + p0_); \
        o4_[0] = make_float4(bufv[0], bufv[1], bufv[2], bufv[3]); \
        o4_[1] = make_float4(bufv[4], bufv[5], bufv[6], bufv[7]); \
    } else { \
        _Pragma("unroll") \
        for (int j = 0; j < 8; ++j) \
            if (p0_ + j < T) orow[p0_ + j] = bufv[j]; \
    } \
    const int kn_ = (k_ + 4 >= NCu) ? (NCu - 1) : (k_ + 4); \
    GLOADQ(QA, cb8 + (size_t)kn_ * 32); \
    GLOADQ(QB, cb8 + (size_t)kn_ * 32 + 16); }

__global__ __launch_bounds__(64, 1) void crf_fb_bt(
    const int*     __restrict__ lengths,
    const uint8_t* __restrict__ bpA,
    const uint8_t* __restrict__ bpC,
    const float*   __restrict__ fvA,
    const float*   __restrict__ hws,
    float*         __restrict__ out_scores,
    float*         __restrict__ out_path,
    int B, int T, int H, int NCpad)
{
    const int rb = (B + 63) >> 6;
    const bool roleA = ((int)blockIdx.x < rb);
    const int s = (roleA ? (int)blockIdx.x : (int)blockIdx.x - rb) * 64 + threadIdx.x;
    if (s >= B) return;
    const int len = lengths[s];
    const int blocksA = H >> 3;
    const int NCu = (T - H + 7) >> 3;

    float fa[8], hh[8];
    {
        const float4* f4 = (const float4*)(fvA + (size_t)s * 8);
        float4 a = f4[0], c = f4[1];
        fa[0]=a.x; fa[1]=a.y; fa[2]=a.z; fa[3]=a.w;
        fa[4]=c.x; fa[5]=c.y; fa[6]=c.z; fa[7]=c.w;
        const float4* h4 = (const float4*)(hws + (size_t)s * 8);
        float4 d = h4[0], e = h4[1];
        hh[0]=d.x; hh[1]=d.y; hh[2]=d.z; hh[3]=d.w;
        hh[4]=e.x; hh[5]=e.y; hh[6]=e.z; hh[7]=e.w;
    }
    float best = fa[0] + hh[0];
    int bstar = 0;
#pragma unroll
    for (int nn = 1; nn < 8; ++nn) {
        const float v = fa[nn] + hh[nn];
        if (v > best) { best = v; bstar = nn; }
    }

    float* orow = out_path + (size_t)s * T;
    int tag = bstar;
    v4i Q0a, Q0b, Q1a, Q1b, Q2a, Q2b, Q3a, Q3b;

    if (roleA) {
        const int lenA = min(len, H);
        const uint8_t* ab8 = bpA + (size_t)s * blocksA * 32;
        const int kt = blocksA - 1;          // kt % 4 == 3 (guarded)
        GLOADQ(Q3a, ab8 + (size_t)kt * 32);       GLOADQ(Q3b, ab8 + (size_t)kt * 32 + 16);
        GLOADQ(Q2a, ab8 + (size_t)(kt - 1) * 32); GLOADQ(Q2b, ab8 + (size_t)(kt - 1) * 32 + 16);
        GLOADQ(Q1a, ab8 + (size_t)(kt - 2) * 32); GLOADQ(Q1b, ab8 + (size_t)(kt - 2) * 32 + 16);
        GLOADQ(Q0a, ab8 + (size_t)(kt - 3) * 32); GLOADQ(Q0b, ab8 + (size_t)(kt - 3) * 32 + 16);
        AITER(kt,     Q3a, Q3b, 6)
        AITER(kt - 1, Q2a, Q2b, 8)
        AITER(kt - 2, Q1a, Q1b, 10)
        AITER(kt - 3, Q0a, Q0b, 12)
        for (int k = kt - 4; k >= 3; k -= 4) {
            AITER(k,     Q3a, Q3b, 12)
            AITER(k - 1, Q2a, Q2b, 12)
            AITER(k - 2, Q1a, Q1b, 12)
            AITER(k - 3, Q0a, Q0b, 12)
        }
    } else {
        out_scores[s] = best;                // before loads: oldest vmem op
        const uint8_t* cb8 = bpC + (size_t)s * NCpad * 32;
        GLOADQ(Q0a, cb8);                    GLOADQ(Q0b, cb8 + 16);
        GLOADQ(Q1a, cb8 + 32);               GLOADQ(Q1b, cb8 + 48);
        GLOADQ(Q2a, cb8 + 64);               GLOADQ(Q2b, cb8 + 80);
        GLOADQ(Q3a, cb8 + 96);               GLOADQ(Q3b, cb8 + 112);
        CITER(0, Q0a, Q0b, 6)
        CITER(1, Q1a, Q1b, 8)
        CITER(2, Q2a, Q2b, 10)
        CITER(3, Q3a, Q3b, 12)
        for (int k = 4; k + 3 < NCu; k += 4) {
            CITER(k,     Q0a, Q0b, 12)
            CITER(k + 1, Q1a, Q1b, 12)
            CITER(k + 2, Q2a, Q2b, 12)
            CITER(k + 3, Q3a, Q3b, 12)
        }
    }
}

// ===========================================================================
// Fallback (ws too small / odd shapes): R8 fused kernel verbatim.
// ===========================================================================
__global__ __launch_bounds__(64, 1) void crf_fused_small(
    const float* __restrict__ feats,
    const int*   __restrict__ lengths,
    const float* __restrict__ trans,
    float*       __restrict__ out_scores,
    float*       __restrict__ out_path,
    uint8_t*     __restrict__ bp4,
    int B, int T)
{
    const int lane = threadIdx.x & 63;
    const int grp  = lane >> 4;
    const int n    = lane & 15;
    const int m    = n & 7;
    const bool odd = (n & 1);
    const int b4   = blockIdx.x * 4;
    const int b    = min(b4 + grp, B - 1);

    const int len = lengths[b];
    const int l0 = lengths[min(b4 + 0, B - 1)];
    const int l1 = lengths[min(b4 + 1, B - 1)];
    const int l2 = lengths[min(b4 + 2, B - 1)];
    const int l3 = lengths[min(b4 + 3, B - 1)];
    const int maxlen = max(max(l0, l1), max(l2, l3));

    int srcv[8];
    srcv[0] = n;
    srcv[1] = DPP_I(n, 0x121);  srcv[2] = DPP_I(n, 0x122);
    srcv[3] = DPP_I(n, 0x123);  srcv[4] = DPP_I(n, 0x124);
    srcv[5] = DPP_I(n, 0x125);  srcv[6] = DPP_I(n, 0x126);
    srcv[7] = DPP_I(n, 0x127);

    float trowR[8];
    int   rsrc[8];
#pragma unroll
    for (int r = 0; r < 8; ++r) {
        const int sq = srcv[r] & 7;
        trowR[r] = trans[m * TAGS + sq];
        rsrc[r]  = sq ^ 7;
    }

    const float* fb = feats + (size_t)b * T * TAGS + m;
    uint8_t* bpb = bp4 + (size_t)b * T * 4 + (n >> 1);
    const bool store_lane = (n < 8) && !odd;

    float fv = trans[m * TAGS + START_TAG] + fb[0];

#define KLEAF_S(r, ctrl) { \
        int rot_ = DPP_I(__float_as_int(fv), (ctrl)); \
        float lv_ = __int_as_float(rot_) + trowR[r]; \
        k##r = __int_as_float((__float_as_int(lv_) & ~7) | rsrc[r]); }

#define STEP_S(TI, FEAT) { \
        const int t_ = (TI); \
        float k0, k1, k2, k3, k4, k5, k6, k7; \
        { float lv_ = fv + trowR[0]; \
          k0 = __int_as_float((__float_as_int(lv_) & ~7) | rsrc[0]); } \
        KLEAF_S(1, 0x121) KLEAF_S(2, 0x122) KLEAF_S(3, 0x123) \
        KLEAF_S(4, 0x124) KLEAF_S(5, 0x125) KLEAF_S(6, 0x126) \
        KLEAF_S(7, 0x127) \
        const float p1_ = maxf3(k0, k1, k2); \
        const float p2_ = maxf3(k3, k4, k5); \
        const float p3_ = maxf3(k6, k7, p1_); \
        const float mm_ = fmaxf(p2_, p3_); \
        const int   idx_  = (__float_as_int(mm_) & 7) ^ 7; \
        const int   pidx_ = DPP_I(idx_, 0xB1); \
        const int   lo_   = odd ? pidx_ : idx_; \
        const int   hi_   = odd ? idx_ : pidx_; \
        const float fvn_  = mm_ + (FEAT); \
        fv = (t_ < len) ? fvn_ : fv; \
        if (t_ < T) { \
            if (store_lane) \
                bpb[(size_t)t_ * 4] = (uint8_t)(lo_ | (hi_ << 4)); \
        } }

    float fc[8], fn[8];
#pragma unroll
    for (int i = 0; i < 8; ++i)
        fc[i] = fb[(size_t)min(1 + i, T - 1) * TAGS];

    for (int t0 = 1; t0 < maxlen; t0 += 8) {
#pragma unroll
        for (int i = 0; i < 8; ++i)
            fn[i] = fb[(size_t)min(t0 + 8 + i, T - 1) * TAGS];

        STEP_S(t0 + 0, fc[0]) STEP_S(t0 + 1, fc[1])
        STEP_S(t0 + 2, fc[2]) STEP_S(t0 + 3, fc[3])
        STEP_S(t0 + 4, fc[4]) STEP_S(t0 + 5, fc[5])
        STEP_S(t0 + 6, fc[6]) STEP_S(t0 + 7, fc[7])

#pragma unroll
        for (int i = 0; i < 8; ++i) fc[i] = fn[i];
    }
#undef KLEAF_S
#undef STEP_S

    const float term = fv + trans[STOP_TAG * TAGS + m];
    float kk = __int_as_float((__float_as_int(term) & ~7) | (m ^ 7));
    kk = fmaxf(kk, __int_as_float(DPP_I(__float_as_int(kk), 0x124)));
    kk = fmaxf(kk, __int_as_float(DPP_I(__float_as_int(kk), 0x122)));
    kk = fmaxf(kk, __int_as_float(DPP_I(__float_as_int(kk), 0x121)));
    int tag = (__float_as_int(kk) & 7) ^ 7;

    if (n == 0)
        out_scores[b] = kk;

    __builtin_amdgcn_s_waitcnt(0);
    __builtin_amdgcn_sched_barrier(0);

    if (n == 0) {
        const uint32_t* rw = (const uint32_t*)(bp4 + (size_t)b * T * 4);
        float* orow = out_path + (size_t)b * T;
        const int NB = (T + 15) / 16;
        uint32_t wA[16], wB[16];

        auto loadblk = [&](int bi, uint32_t* w) {
            if (bi < 0) return;
#pragma unroll
            for (int j = 0; j < 4; ++j) {
                const int tb = min(bi * 16 + 4 * j, T - 4);
                *(uint4*)&w[4 * j] = *(const uint4*)&rw[tb];
            }
        };
        auto compblk = [&](int bi, uint32_t* w) {
            float buf[16];
#pragma unroll
            for (int u = 15; u >= 0; --u) {
                const int t = bi * 16 + u;
                if (t < T) {
                    const bool act = t < len;
                    buf[u] = act ? (float)tag : 0.0f;
                    if (act) tag = (int)((w[u] >> (4 * tag)) & 15);
                }
            }
#pragma unroll
            for (int j = 0; j < 16; j += 4) {
                const int t = bi * 16 + j;
                if (t + 3 < T)
                    *(float4*)(orow + t) = make_float4(buf[j], buf[j+1], buf[j+2], buf[j+3]);
            }
        };

        int bi = NB - 1;
        loadblk(bi, wA);
        loadblk(bi - 1, wB);
        for (; bi >= 0; bi -= 2) {
            compblk(bi, wA);
            loadblk(bi - 2, wA);
            if (bi - 1 >= 0) compblk(bi - 1, wB);
            loadblk(bi - 3, wB);
        }
    }
}

extern "C" void kernel_launch(void* const* d_in, const int* in_sizes, int n_in,
                              void* d_out, int out_size, void* d_ws, size_t ws_size,
                              hipStream_t stream)
{
    const float* feats   = (const float*)d_in[0];
    const int*   lengths = (const int*)d_in[1];
    const float* trans   = (const float*)d_in[2];
    const int B = in_sizes[1];
    const int T = in_sizes[0] / (B * TAGS);

    float* out_scores = (float*)d_out;       // [B]
    float* out_path   = (float*)d_out + B;   // [B, T] tags as floats

    const int H = ((T / 2) + 15) & ~15;      // seam, multiple of 16
    const int blocksA = H >> 3;
    const int NCu = (T - H + 7) >> 3;
    const int NCpad = ((NCu + 3) / 3) * 3;   // K1-C writes up to block NCpad-1

    const size_t szA = (size_t)B * blocksA * 32;
    const size_t szC = (size_t)B * NCpad * 32;
    const size_t need = szA + szC + (size_t)B * 64 + (size_t)B * 4;

    const bool ok = (H >= 32) && (T > H + 1) && ((T & 3) == 0) && ((B & 3) == 0)
                    && ((blocksA & 3) == 0) && ((NCu & 3) == 0)
                    && (blocksA >= 8) && (NCu >= 8) && (need <= ws_size);

    if (ok) {
        uint8_t* bpA  = (uint8_t*)d_ws;
        uint8_t* bpC  = bpA + szA;
        float*   fvAo = (float*)(bpC + szC);
        float*   hws  = fvAo + (size_t)B * 8;
        int*     ord  = (int*)(hws + (size_t)B * 8);
        const int ABLK = B / 4;

        crf_sort<<<1, 1024, 0, stream>>>(lengths, ord, B);

        crf_fb_fwd<<<2 * ABLK, 64, 0, stream>>>(
            feats, lengths, trans, ord, bpA, bpC, fvAo, hws, B, T, H, ABLK, NCpad);

        const int rb = (B + 63) >> 6;
        crf_fb_bt<<<2 * rb, 64, 0, stream>>>(
            lengths, bpA, bpC, fvAo, hws, out_scores, out_path, B, T, H, NCpad);
    } else {
        uint8_t* bp4 = (uint8_t*)d_ws;       // [B][T] 4B words
        crf_fused_small<<<(B + 3) / 4, 64, 0, stream>>>(
            feats, lengths, trans, out_scores, out_path, bp4, B, T);
    }
}